// Round 13
// baseline (349.920 us; speedup 1.0000x reference)
//
#include <hip/hip_runtime.h>
#include <hip/hip_fp16.h>

#define NN 100000          // N_NODES
#define ED 64              // EMB_DIM
#define NE 3200000         // N_EDGES
#define BSH 9              // log2 nodes per bucket
#define BNODES 512
#define NBUCK 196          // ceil(NN/BNODES)
#define CAP 17408          // slots per bucket (mean 16327, +8 sigma), mult of 64
#define PCAP 18944         // CAP + 512*3 pad headroom, mult of 64
#define CHUNK 8192
#define PTH 512
#define C64 0x64646464u
#define INV512 (1.0f / 512.0f)

union U32H2 { unsigned u; __half2 h; };
__device__ __forceinline__ float h2lo(unsigned u) { U32H2 c; c.u = u; return __low2float(c.h); }
__device__ __forceinline__ float h2hi(unsigned u) { U32H2 c; c.u = u; return __high2float(c.h); }

// softmax(attn weights) + init bucket cursors gcur[b] = b*CAP
__global__ void k_init(const float* __restrict__ w, float* __restrict__ attn,
                       int* __restrict__ gcur) {
    int t = threadIdx.x;
    if (t < NBUCK) gcur[t] = t * CAP;
    if (t == 0) {
        float m = fmaxf(fmaxf(w[0], w[1]), fmaxf(w[2], w[3]));
        float e0 = expf(w[0] - m), e1 = expf(w[1] - m), e2 = expf(w[2] - m), e3 = expf(w[3] - m);
        float s = e0 + e1 + e2 + e3;
        attn[0] = e0 / s; attn[1] = e1 / s; attn[2] = e2 / s; attn[3] = e3 / s;
    }
}

// pass 1: partition edges into fixed-CAP dst-buckets. 4 edges/thread.
// entry u64 = eattr fp16 <<32 | dl 9b <<17 | src 17b, eattr = exp(scale*attr)
__global__ void __launch_bounds__(PTH) k_part(const int* __restrict__ src,
        const int* __restrict__ dst, const float* __restrict__ attr,
        const float* __restrict__ scale,
        int* __restrict__ gcur, unsigned long long* __restrict__ part) {
    __shared__ unsigned long long stage[CHUNK];   // 64 KiB
    __shared__ int hist[NBUCK];
    __shared__ int lstart[NBUCK + 1];
    __shared__ int gbase[NBUCK];
    __shared__ unsigned char bkof[CHUNK];         // 8 KiB
    const int tid = threadIdx.x;
    const int base = blockIdx.x * CHUNK;
    const int n = min(CHUNK, NE - base);
    for (int i = tid; i < NBUCK; i += PTH) hist[i] = 0;
    __syncthreads();
    for (int i = tid * 4; i < n; i += PTH * 4) {
        int4 d4 = *reinterpret_cast<const int4*>(dst + base + i);
        atomicAdd(&hist[d4.x >> BSH], 1); atomicAdd(&hist[d4.y >> BSH], 1);
        atomicAdd(&hist[d4.z >> BSH], 1); atomicAdd(&hist[d4.w >> BSH], 1);
    }
    __syncthreads();
    if (tid < 64) {                                // exclusive scan of hist
        int carry = 0;
        #pragma unroll
        for (int g = 0; g < 4; ++g) {
            int b = g * 64 + tid;
            int v = (b < NBUCK) ? hist[b] : 0;
            int s = v;
            #pragma unroll
            for (int o = 1; o < 64; o <<= 1) { int t = __shfl_up(s, o, 64); if (tid >= o) s += t; }
            if (b < NBUCK) lstart[b] = carry + s - v;
            carry += __shfl(s, 63, 64);
        }
        if (tid == 0) lstart[NBUCK] = n;
    }
    __syncthreads();
    for (int b = tid; b < NBUCK; b += PTH) {
        int cnt = lstart[b + 1] - lstart[b];
        gbase[b] = atomicAdd(&gcur[b], cnt);
        hist[b] = lstart[b];
    }
    __syncthreads();
    const float sc = scale[0];
    for (int i = tid * 4; i < n; i += PTH * 4) {
        int4 s4 = *reinterpret_cast<const int4*>(src + base + i);
        int4 d4 = *reinterpret_cast<const int4*>(dst + base + i);
        float4 a4 = *reinterpret_cast<const float4*>(attr + base + i);
        #pragma unroll
        for (int k = 0; k < 4; ++k) {
            int s = (k == 0) ? s4.x : (k == 1) ? s4.y : (k == 2) ? s4.z : s4.w;
            int d = (k == 0) ? d4.x : (k == 1) ? d4.y : (k == 2) ? d4.z : d4.w;
            float a = (k == 0) ? a4.x : (k == 1) ? a4.y : (k == 2) ? a4.z : a4.w;
            unsigned short ea = __half_as_ushort(__float2half(expf(sc * a)));
            int bk = d >> BSH;
            int p = atomicAdd(&hist[bk], 1);
            stage[p] = ((unsigned long long)ea << 32)
                     | (unsigned)(s | ((d & (BNODES - 1)) << 17));
            bkof[p] = (unsigned char)bk;
        }
    }
    __syncthreads();
    for (int i = tid; i < n; i += PTH) {
        int bk = bkof[i];
        part[(size_t)gbase[bk] + (i - lstart[bk])] = stage[i];
    }
}

// merged build: per-bucket histogram -> padded scan -> placement.
// eq <- src (low 17 bits; weight bits filled by k_fold), ewb <- fp16 dinv[dst]*eattr
__global__ void __launch_bounds__(1024) k_build(const int* __restrict__ gcur,
        const unsigned long long* __restrict__ part,
        int* __restrict__ rowptr, unsigned short* __restrict__ pdeg16,
        float* __restrict__ dinvf, unsigned* __restrict__ eq, __half* __restrict__ ewb) {
    __shared__ int deg[BNODES];
    __shared__ int cur[BNODES];
    __shared__ float dli[BNODES];
    __shared__ int wsum[8];
    const int b = blockIdx.x, tid = threadIdx.x;
    const int rs = b * CAP, re = gcur[b];
    if (tid < BNODES) deg[tid] = 0;
    __syncthreads();
    for (int j = rs + tid; j < re; j += 1024) {
        unsigned lo = (unsigned)part[j];
        atomicAdd(&deg[(lo >> 17) & (BNODES - 1)], 1);
    }
    __syncthreads();
    int start = 0, pd = 0, d = 0;
    if (tid < BNODES) {
        const int lane = tid & 63, wv = tid >> 6;
        d = deg[tid];
        pd = (d + 3) & ~3;
        int x = pd;
        #pragma unroll
        for (int o = 1; o < 64; o <<= 1) { int t = __shfl_up(x, o, 64); if (lane >= o) x += t; }
        if (lane == 63) wsum[wv] = x;
        __syncthreads();
        if (tid < 8) {
            int orig = wsum[tid]; int t = orig;
            #pragma unroll
            for (int o = 1; o < 8; o <<= 1) { int u = __shfl_up(t, o, 64); if (tid >= o) t += u; }
            wsum[tid] = t - orig;
        }
        __syncthreads();
        int node = b * BNODES + tid;
        start = b * PCAP + wsum[wv] + (x - pd);
        cur[tid] = start;
        float dv = (d > 0) ? rsqrtf((float)d) : 0.0f;
        dli[tid] = dv;
        if (node < NN) {
            rowptr[node] = start;
            pdeg16[node] = (unsigned short)pd;
            dinvf[node] = dv;
        }
    } else {
        __syncthreads();
        __syncthreads();
    }
    __syncthreads();
    // placement pass
    for (int j = rs + tid; j < re; j += 1024) {
        unsigned long long v = part[j];
        unsigned lo = (unsigned)v;
        int s  = lo & 0x1FFFF;
        int dl = (lo >> 17) & (BNODES - 1);
        float ea = __half2float(__ushort_as_half((unsigned short)(v >> 32)));
        float w = dli[dl] * ea;
        int p = atomicAdd(&cur[dl], 1);
        eq[p] = (unsigned)s;
        ewb[p] = __float2half(w);
    }
    __syncthreads();
    if (tid < BNODES) {                            // zero the <=3 pad slots per row
        int fin = start + pd;
        for (int p = cur[tid]; p < fin; ++p) { eq[p] = 0u; ewb[p] = __ushort_as_half((unsigned short)0); }
    }
}

// quantize emb rows -> int8 (biased) + per-row scale. 16 lanes per row.
__global__ void k_prep(const float* __restrict__ emb, unsigned* __restrict__ xq,
                       float* __restrict__ xs) {
    int t = blockIdx.x * 256 + threadIdx.x;   // grid 6250 exact
    int row = t >> 4, gi = t & 15;
    float4 e = reinterpret_cast<const float4*>(emb)[t];
    float m = fmaxf(fmaxf(fabsf(e.x), fabsf(e.y)), fmaxf(fabsf(e.z), fabsf(e.w)));
    m = fmaxf(m, __shfl_xor(m, 1, 64));
    m = fmaxf(m, __shfl_xor(m, 2, 64));
    m = fmaxf(m, __shfl_xor(m, 4, 64));
    m = fmaxf(m, __shfl_xor(m, 8, 64));
    float inv = (m > 0.0f) ? 127.0f / m : 0.0f;
    int q0 = (int)rintf(e.x * inv) + 128;
    int q1 = (int)rintf(e.y * inv) + 128;
    int q2 = (int)rintf(e.z * inv) + 128;
    int q3 = (int)rintf(e.w * inv) + 128;
    unsigned u = (unsigned)(q0 & 0xFF) | ((unsigned)(q1 & 0xFF) << 8)
               | ((unsigned)(q2 & 0xFF) << 16) | ((unsigned)(q3 & 0xFF) << 24);
    xq[t] = u;
    if (gi == 0) xs[row] = m * (1.0f / 127.0f);
}

// per-layer scale table: tabh[n] = fp16( dinv[n] * xs[n] * 512 )
__global__ void k_tab(const float* __restrict__ dinvf, const float* __restrict__ xs,
                      unsigned short* __restrict__ tabh) {
    int n = blockIdx.x * 256 + threadIdx.x;
    if (n < NN) tabh[n] = __half_as_ushort(__float2half(dinvf[n] * xs[n] * 512.0f));
}

// in-place fold: eq[i] = ( fp16(ewb[i] * tabh[src]) << 17 ) | src
// src recovered from eq's own low 17 bits (preserved across layers).
// Processes ALL PSLOTS slots; garbage slots are memory-safe (tabh 2^17 entries).
__global__ void k_fold(unsigned* __restrict__ eq, const unsigned short* __restrict__ ewb,
                       const unsigned short* __restrict__ tabh) {
    int i = (blockIdx.x * 256 + threadIdx.x) * 4;   // grid 3626 exact over PSLOTS
    uint4 e4 = *reinterpret_cast<const uint4*>(eq + i);
    ushort4 w4 = *reinterpret_cast<const ushort4*>(ewb + i);
    unsigned s0 = e4.x & 0x1FFFFu, s1 = e4.y & 0x1FFFFu;
    unsigned s2 = e4.z & 0x1FFFFu, s3 = e4.w & 0x1FFFFu;
    unsigned h0 = (unsigned)__half_as_ushort(__hmul(__ushort_as_half(w4.x), __ushort_as_half(tabh[s0])));
    unsigned h1 = (unsigned)__half_as_ushort(__hmul(__ushort_as_half(w4.y), __ushort_as_half(tabh[s1])));
    unsigned h2 = (unsigned)__half_as_ushort(__hmul(__ushort_as_half(w4.z), __ushort_as_half(tabh[s2])));
    unsigned h3 = (unsigned)__half_as_ushort(__hmul(__ushort_as_half(w4.w), __ushort_as_half(tabh[s3])));
    uint4 o;
    o.x = (h0 << 17) | s0; o.y = (h1 << 17) | s1;
    o.z = (h2 << 17) | s2; o.w = (h3 << 17) | s3;
    *reinterpret_cast<uint4*>(eq + i) = o;
}

// gather: one wave per node; 4 lane-groups of 16 handle 4 edges (a quad);
// edge record u32 = fp15 weight<<17 | src (nt load); lane loads u32 = 4
// biased-int8 dims; perm-magic dequant; hfma2. 32-edge main, 4-edge tail.
// Non-FINAL: quantize output row to int8+scale. FINAL: fused 4-way combine.
template <bool FINAL>
__global__ void __launch_bounds__(256) k_gather(const int* __restrict__ rowptr,
        const unsigned short* __restrict__ pdeg16,
        const unsigned* __restrict__ eq,
        const unsigned* __restrict__ xq, unsigned* __restrict__ yq,
        float* __restrict__ ys, const float* __restrict__ emb,
        const unsigned* __restrict__ y1q, const float* __restrict__ y1s,
        const float* __restrict__ y2s, const float* __restrict__ attnp,
        float* __restrict__ out0, float* __restrict__ acc) {
    int gt = blockIdx.x * 256 + threadIdx.x;   // grid = NN*64/256 = 25000 exact
    int nid = gt >> 6;                         // wave-uniform
    int lane = gt & 63;
    int g = lane >> 4;                         // edge slot 0..3 within quad
    int gi = lane & 15;                        // 4-dim chunk index
    int beg = __builtin_amdgcn_readfirstlane(rowptr[nid]);
    int pd  = __builtin_amdgcn_readfirstlane((int)pdeg16[nid]);
    int end = beg + pd;
    const unsigned* eqg = eq + g;
    U32H2 BIAS; BIAS.u = 0x64806480u;          // half2 {1152, 1152}
    __half2 z = __float2half2_rn(0.0f);
    __half2 pa0 = z, pa1 = z, pb0 = z, pb1 = z;

#define QE(J, A0, A1) { \
    unsigned eu = __builtin_nontemporal_load(eqg + (J)); \
    unsigned s = eu & 0x1FFFFu; \
    unsigned wu = eu >> 17; \
    U32H2 wd; wd.u = __builtin_amdgcn_perm(wu, wu, 0x01000100u); \
    unsigned ch = xq[(s << 4) | (unsigned)gi]; \
    U32H2 h0; h0.u = __builtin_amdgcn_perm(C64, ch, 0x04010400u); \
    U32H2 h1; h1.u = __builtin_amdgcn_perm(C64, ch, 0x04030402u); \
    A0 = __hfma2(wd.h, __hsub2(h0.h, BIAS.h), A0); \
    A1 = __hfma2(wd.h, __hsub2(h1.h, BIAS.h), A1); }

    int j = beg;
    int n32 = beg + (pd & ~31);
    for (; j < n32; j += 32) {
        QE(j,      pa0, pa1); QE(j + 4,  pb0, pb1);
        QE(j + 8,  pa0, pa1); QE(j + 12, pb0, pb1);
        QE(j + 16, pa0, pa1); QE(j + 20, pb0, pb1);
        QE(j + 24, pa0, pa1); QE(j + 28, pb0, pb1);
    }
    for (; j < end; j += 4) {                  // 4-edge tail (<=7 iters, uniform)
        QE(j, pa0, pa1);
    }
#undef QE

    float2 fa0 = __half22float2(pa0), fb0 = __half22float2(pb0);
    float2 fa1 = __half22float2(pa1), fb1 = __half22float2(pb1);
    float a0 = (fa0.x + fb0.x) * INV512;       // dim 4gi+0
    float a1 = (fa0.y + fb0.y) * INV512;       // dim 4gi+1
    float a2 = (fa1.x + fb1.x) * INV512;       // dim 4gi+2
    float a3 = (fa1.y + fb1.y) * INV512;       // dim 4gi+3
    a0 += __shfl_xor(a0, 16, 64); a0 += __shfl_xor(a0, 32, 64);
    a1 += __shfl_xor(a1, 16, 64); a1 += __shfl_xor(a1, 32, 64);
    a2 += __shfl_xor(a2, 16, 64); a2 += __shfl_xor(a2, 32, 64);
    a3 += __shfl_xor(a3, 16, 64); a3 += __shfl_xor(a3, 32, 64);
    if (lane < 16) {
        unsigned ri = (unsigned)(nid << 4) | (unsigned)gi;
        if (!FINAL) {
            float m = fmaxf(fmaxf(fabsf(a0), fabsf(a1)), fmaxf(fabsf(a2), fabsf(a3)));
            m = fmaxf(m, __shfl_xor(m, 1, 64));
            m = fmaxf(m, __shfl_xor(m, 2, 64));
            m = fmaxf(m, __shfl_xor(m, 4, 64));
            m = fmaxf(m, __shfl_xor(m, 8, 64));
            float inv = (m > 0.0f) ? 127.0f / m : 0.0f;
            int q0 = (int)rintf(a0 * inv) + 128;
            int q1 = (int)rintf(a1 * inv) + 128;
            int q2 = (int)rintf(a2 * inv) + 128;
            int q3 = (int)rintf(a3 * inv) + 128;
            unsigned u = (unsigned)(q0 & 0xFF) | ((unsigned)(q1 & 0xFF) << 8)
                       | ((unsigned)(q2 & 0xFF) << 16) | ((unsigned)(q3 & 0xFF) << 24);
            yq[ri] = u;
            if (gi == 0) ys[nid] = m * (1.0f / 127.0f);
        } else {
            float w0 = attnp[0], w1 = attnp[1], w2 = attnp[2], w3 = attnp[3];
            float4 e = reinterpret_cast<const float4*>(emb)[ri];
            float s1 = y1s[nid], s2 = y2s[nid];
            unsigned u1 = y1q[ri], u2 = xq[ri];         // xq == y2q
            U32H2 d10, d11, d20, d21;
            d10.u = __builtin_amdgcn_perm(C64, u1, 0x04010400u);
            d11.u = __builtin_amdgcn_perm(C64, u1, 0x04030402u);
            d20.u = __builtin_amdgcn_perm(C64, u2, 0x04010400u);
            d21.u = __builtin_amdgcn_perm(C64, u2, 0x04030402u);
            float2 p10 = __half22float2(__hsub2(d10.h, BIAS.h));
            float2 p11 = __half22float2(__hsub2(d11.h, BIAS.h));
            float2 p20 = __half22float2(__hsub2(d20.h, BIAS.h));
            float2 p21 = __half22float2(__hsub2(d21.h, BIAS.h));
            float4 r;
            r.x = w0 * e.x + w1 * (p10.x * s1) + w2 * (p20.x * s2) + w3 * a0;
            r.y = w0 * e.y + w1 * (p10.y * s1) + w2 * (p20.y * s2) + w3 * a1;
            r.z = w0 * e.z + w1 * (p11.x * s1) + w2 * (p21.x * s2) + w3 * a2;
            r.w = w0 * e.w + w1 * (p11.y * s1) + w2 * (p21.y * s2) + w3 * a3;
            reinterpret_cast<float4*>(out0)[ri] = e;
            reinterpret_cast<float4*>(acc)[ri] = r;
        }
    }
}

extern "C" void kernel_launch(void* const* d_in, const int* in_sizes, int n_in,
                              void* d_out, int out_size, void* d_ws, size_t ws_size,
                              hipStream_t stream) {
    const float* emb   = (const float*)d_in[0];
    const float* attw  = (const float*)d_in[1];
    const float* scale = (const float*)d_in[2];
    const float* attr  = (const float*)d_in[3];
    const int*   ei    = (const int*)d_in[4];
    const int* src = ei;
    const int* dst = ei + NE;

    float* out0 = (float*)d_out;
    float* acc  = out0 + (size_t)NN * ED;

    // workspace (~51.2 MB). part (27.3MB) dead after k_build -> aliased by
    // the quantized x/y buffers (3 x 6.8MB).
    const size_t SLOTS  = (size_t)NBUCK * CAP;    // 3,411,968 (part)
    const size_t PSLOTS = (size_t)NBUCK * PCAP;   // 3,713,024 (eq/ewb)
    char* ws = (char*)d_ws;
    size_t off = 0;
    float*  attn   = (float*)(ws + off); off += 256;
    int*    gcur   = (int*)(ws + off);   off += 1024;
    float*  dinvf  = (float*)(ws + off); off += ((size_t)NN * 4 + 255) & ~(size_t)255;
    int*    rowptr = (int*)(ws + off);   off += ((size_t)NN * 4 + 255) & ~(size_t)255;
    unsigned short* pdeg16 = (unsigned short*)(ws + off); off += ((size_t)NN * 2 + 255) & ~(size_t)255;
    unsigned short* tabh   = (unsigned short*)(ws + off); off += (size_t)131072 * 2;  // 2^17 entries
    char*   partc  = ws + off;           off += SLOTS * 8;
    unsigned long long* part = (unsigned long long*)partc;
    unsigned* eq   = (unsigned*)(ws + off); off += PSLOTS * 4;
    __half* ewb    = (__half*)(ws + off);   off += PSLOTS * 2;
    // aliases into dead part region (written only after k_build):
    const size_t QROW = (size_t)NN * ED;          // 6,400,000 bytes (u8)
    const size_t SSZ  = ((size_t)NN * 4 + 383) & ~(size_t)255;   // 400,384
    unsigned* xq0 = (unsigned*)(partc);
    float*    xs0 = (float*)(partc + QROW);
    unsigned* y1q = (unsigned*)(partc + QROW + SSZ);
    float*    y1s = (float*)(partc + 2 * QROW + SSZ);
    unsigned* y2q = (unsigned*)(partc + 2 * QROW + 2 * SSZ);
    float*    y2s = (float*)(partc + 3 * QROW + 2 * SSZ);

    const int QB = (NN * 16) / 256;            // 6250 exact (k_prep)
    const int GB = (NN * ED) / 256;            // 25000 exact
    const int PB = (NE + CHUNK - 1) / CHUNK;   // 391
    const int NB = (NN + 255) / 256;           // 391 (k_tab)
    const int FB = (int)(PSLOTS / 4 / 256);    // 3626 exact (k_fold)

    k_init<<<1, 256, 0, stream>>>(attw, attn, gcur);
    k_part<<<PB, PTH, 0, stream>>>(src, dst, attr, scale, gcur, part);
    k_build<<<NBUCK, 1024, 0, stream>>>(gcur, part, rowptr, pdeg16, dinvf, eq, ewb);
    // part dead from here; quantized buffers alias it
    k_prep<<<QB, 256, 0, stream>>>(emb, xq0, xs0);

    k_tab<<<NB, 256, 0, stream>>>(dinvf, xs0, tabh);
    k_fold<<<FB, 256, 0, stream>>>(eq, (const unsigned short*)ewb, tabh);
    k_gather<false><<<GB, 256, 0, stream>>>(rowptr, pdeg16, eq, xq0, y1q, y1s,
        nullptr, nullptr, nullptr, nullptr, nullptr, nullptr, nullptr);

    k_tab<<<NB, 256, 0, stream>>>(dinvf, y1s, tabh);
    k_fold<<<FB, 256, 0, stream>>>(eq, (const unsigned short*)ewb, tabh);
    k_gather<false><<<GB, 256, 0, stream>>>(rowptr, pdeg16, eq, y1q, y2q, y2s,
        nullptr, nullptr, nullptr, nullptr, nullptr, nullptr, nullptr);

    k_tab<<<NB, 256, 0, stream>>>(dinvf, y2s, tabh);
    k_fold<<<FB, 256, 0, stream>>>(eq, (const unsigned short*)ewb, tabh);
    k_gather<true><<<GB, 256, 0, stream>>>(rowptr, pdeg16, eq, y2q, nullptr, nullptr,
        emb, y1q, y1s, y2s, attn, out0, acc);
}

// Round 14
// 289.151 us; speedup vs baseline: 1.2102x; 1.2102x over previous
//
#include <hip/hip_runtime.h>
#include <hip/hip_fp16.h>

#define NN 100000          // N_NODES
#define ED 64              // EMB_DIM
#define NE 3200000         // N_EDGES
#define BSH 9              // log2 nodes per bucket
#define BNODES 512
#define NBUCK 196          // ceil(NN/BNODES)
#define CAP 17408          // slots per bucket (mean 16327, +8 sigma), mult of 64
#define PCAP 18944         // CAP + 512*3 pad headroom, mult of 64
#define CHUNK 8192
#define PTH 512
#define C64 0x64646464u
#define INV512 (1.0f / 512.0f)

union U32H2 { unsigned u; __half2 h; };
__device__ __forceinline__ float h2lo(unsigned u) { U32H2 c; c.u = u; return __low2float(c.h); }
__device__ __forceinline__ float h2hi(unsigned u) { U32H2 c; c.u = u; return __high2float(c.h); }

// softmax(attn weights) + init bucket cursors gcur[b] = b*CAP
__global__ void k_init(const float* __restrict__ w, float* __restrict__ attn,
                       int* __restrict__ gcur) {
    int t = threadIdx.x;
    if (t < NBUCK) gcur[t] = t * CAP;
    if (t == 0) {
        float m = fmaxf(fmaxf(w[0], w[1]), fmaxf(w[2], w[3]));
        float e0 = expf(w[0] - m), e1 = expf(w[1] - m), e2 = expf(w[2] - m), e3 = expf(w[3] - m);
        float s = e0 + e1 + e2 + e3;
        attn[0] = e0 / s; attn[1] = e1 / s; attn[2] = e2 / s; attn[3] = e3 / s;
    }
}

// pass 1: partition edges into fixed-CAP dst-buckets. 4 edges/thread.
// entry u64 = eattr fp16 <<32 | dl 9b <<17 | src 17b, eattr = exp(scale*attr)
__global__ void __launch_bounds__(PTH) k_part(const int* __restrict__ src,
        const int* __restrict__ dst, const float* __restrict__ attr,
        const float* __restrict__ scale,
        int* __restrict__ gcur, unsigned long long* __restrict__ part) {
    __shared__ unsigned long long stage[CHUNK];   // 64 KiB
    __shared__ int hist[NBUCK];
    __shared__ int lstart[NBUCK + 1];
    __shared__ int gbase[NBUCK];
    __shared__ unsigned char bkof[CHUNK];         // 8 KiB
    const int tid = threadIdx.x;
    const int base = blockIdx.x * CHUNK;
    const int n = min(CHUNK, NE - base);
    for (int i = tid; i < NBUCK; i += PTH) hist[i] = 0;
    __syncthreads();
    for (int i = tid * 4; i < n; i += PTH * 4) {
        int4 d4 = *reinterpret_cast<const int4*>(dst + base + i);
        atomicAdd(&hist[d4.x >> BSH], 1); atomicAdd(&hist[d4.y >> BSH], 1);
        atomicAdd(&hist[d4.z >> BSH], 1); atomicAdd(&hist[d4.w >> BSH], 1);
    }
    __syncthreads();
    if (tid < 64) {                                // exclusive scan of hist
        int carry = 0;
        #pragma unroll
        for (int g = 0; g < 4; ++g) {
            int b = g * 64 + tid;
            int v = (b < NBUCK) ? hist[b] : 0;
            int s = v;
            #pragma unroll
            for (int o = 1; o < 64; o <<= 1) { int t = __shfl_up(s, o, 64); if (tid >= o) s += t; }
            if (b < NBUCK) lstart[b] = carry + s - v;
            carry += __shfl(s, 63, 64);
        }
        if (tid == 0) lstart[NBUCK] = n;
    }
    __syncthreads();
    for (int b = tid; b < NBUCK; b += PTH) {
        int cnt = lstart[b + 1] - lstart[b];
        gbase[b] = atomicAdd(&gcur[b], cnt);
        hist[b] = lstart[b];
    }
    __syncthreads();
    const float sc = scale[0];
    for (int i = tid * 4; i < n; i += PTH * 4) {
        int4 s4 = *reinterpret_cast<const int4*>(src + base + i);
        int4 d4 = *reinterpret_cast<const int4*>(dst + base + i);
        float4 a4 = *reinterpret_cast<const float4*>(attr + base + i);
        #pragma unroll
        for (int k = 0; k < 4; ++k) {
            int s = (k == 0) ? s4.x : (k == 1) ? s4.y : (k == 2) ? s4.z : s4.w;
            int d = (k == 0) ? d4.x : (k == 1) ? d4.y : (k == 2) ? d4.z : d4.w;
            float a = (k == 0) ? a4.x : (k == 1) ? a4.y : (k == 2) ? a4.z : a4.w;
            unsigned short ea = __half_as_ushort(__float2half(expf(sc * a)));
            int bk = d >> BSH;
            int p = atomicAdd(&hist[bk], 1);
            stage[p] = ((unsigned long long)ea << 32)
                     | (unsigned)(s | ((d & (BNODES - 1)) << 17));
            bkof[p] = (unsigned char)bk;
        }
    }
    __syncthreads();
    for (int i = tid; i < n; i += PTH) {
        int bk = bkof[i];
        part[(size_t)gbase[bk] + (i - lstart[bk])] = stage[i];
    }
}

// merged build: per-bucket histogram -> padded scan -> placement.
// estat[p] = ( fp15(dinv[dst]*eattr) << 17 ) | src   (static, no per-layer data)
__global__ void __launch_bounds__(1024) k_build(const int* __restrict__ gcur,
        const unsigned long long* __restrict__ part,
        int* __restrict__ rowptr, unsigned short* __restrict__ pdeg16,
        float* __restrict__ dinvf, unsigned* __restrict__ estat) {
    __shared__ int deg[BNODES];
    __shared__ int cur[BNODES];
    __shared__ float dli[BNODES];
    __shared__ int wsum[8];
    const int b = blockIdx.x, tid = threadIdx.x;
    const int rs = b * CAP, re = gcur[b];
    if (tid < BNODES) deg[tid] = 0;
    __syncthreads();
    for (int j = rs + tid; j < re; j += 1024) {
        unsigned lo = (unsigned)part[j];
        atomicAdd(&deg[(lo >> 17) & (BNODES - 1)], 1);
    }
    __syncthreads();
    int start = 0, pd = 0, d = 0;
    if (tid < BNODES) {
        const int lane = tid & 63, wv = tid >> 6;
        d = deg[tid];
        pd = (d + 3) & ~3;
        int x = pd;
        #pragma unroll
        for (int o = 1; o < 64; o <<= 1) { int t = __shfl_up(x, o, 64); if (lane >= o) x += t; }
        if (lane == 63) wsum[wv] = x;
        __syncthreads();
        if (tid < 8) {
            int orig = wsum[tid]; int t = orig;
            #pragma unroll
            for (int o = 1; o < 8; o <<= 1) { int u = __shfl_up(t, o, 64); if (tid >= o) t += u; }
            wsum[tid] = t - orig;
        }
        __syncthreads();
        int node = b * BNODES + tid;
        start = b * PCAP + wsum[wv] + (x - pd);
        cur[tid] = start;
        float dv = (d > 0) ? rsqrtf((float)d) : 0.0f;
        dli[tid] = dv;
        if (node < NN) {
            rowptr[node] = start;
            pdeg16[node] = (unsigned short)pd;
            dinvf[node] = dv;
        }
    } else {
        __syncthreads();
        __syncthreads();
    }
    __syncthreads();
    // placement pass
    for (int j = rs + tid; j < re; j += 1024) {
        unsigned long long v = part[j];
        unsigned lo = (unsigned)v;
        unsigned s = lo & 0x1FFFFu;
        int dl = (lo >> 17) & (BNODES - 1);
        float ea = __half2float(__ushort_as_half((unsigned short)(v >> 32)));
        float w = dli[dl] * ea;                    // >= 0, fp16 sign bit = 0
        unsigned hw = (unsigned)__half_as_ushort(__float2half(w));
        int p = atomicAdd(&cur[dl], 1);
        estat[p] = (hw << 17) | s;
    }
    __syncthreads();
    if (tid < BNODES) {                            // zero the <=3 pad slots per row
        int fin = start + pd;
        for (int p = cur[tid]; p < fin; ++p) estat[p] = 0u;
    }
}

// quantize emb rows -> int8 (biased) + per-row scale. 16 lanes per row.
__global__ void k_prep(const float* __restrict__ emb, unsigned* __restrict__ xq,
                       float* __restrict__ xs) {
    int t = blockIdx.x * 256 + threadIdx.x;   // grid 6250 exact
    int row = t >> 4, gi = t & 15;
    float4 e = reinterpret_cast<const float4*>(emb)[t];
    float m = fmaxf(fmaxf(fabsf(e.x), fabsf(e.y)), fmaxf(fabsf(e.z), fabsf(e.w)));
    m = fmaxf(m, __shfl_xor(m, 1, 64));
    m = fmaxf(m, __shfl_xor(m, 2, 64));
    m = fmaxf(m, __shfl_xor(m, 4, 64));
    m = fmaxf(m, __shfl_xor(m, 8, 64));
    float inv = (m > 0.0f) ? 127.0f / m : 0.0f;
    int q0 = (int)rintf(e.x * inv) + 128;
    int q1 = (int)rintf(e.y * inv) + 128;
    int q2 = (int)rintf(e.z * inv) + 128;
    int q3 = (int)rintf(e.w * inv) + 128;
    unsigned u = (unsigned)(q0 & 0xFF) | ((unsigned)(q1 & 0xFF) << 8)
               | ((unsigned)(q2 & 0xFF) << 16) | ((unsigned)(q3 & 0xFF) << 24);
    xq[t] = u;
    if (gi == 0) xs[row] = m * (1.0f / 127.0f);
}

// per-layer scale table: tabh[n] = fp16( dinv[n] * xs[n] * 512 )
__global__ void k_tab(const float* __restrict__ dinvf, const float* __restrict__ xs,
                      unsigned short* __restrict__ tabh) {
    int n = blockIdx.x * 256 + threadIdx.x;
    if (n < NN) tabh[n] = __half_as_ushort(__float2half(dinvf[n] * xs[n] * 512.0f));
}

// fold: eqf[i] = ( fp15(estat.w * tabh[src]) << 17 ) | src. One streaming pass.
// Processes ALL PSLOTS slots; garbage slots are memory-safe (tabh 2^17 entries).
__global__ void k_fold(const unsigned* __restrict__ estat, unsigned* __restrict__ eqf,
                       const unsigned short* __restrict__ tabh) {
    int i = (blockIdx.x * 256 + threadIdx.x) * 4;   // grid 3626 exact over PSLOTS
    uint4 e4 = *reinterpret_cast<const uint4*>(estat + i);
    unsigned s0 = e4.x & 0x1FFFFu, s1 = e4.y & 0x1FFFFu;
    unsigned s2 = e4.z & 0x1FFFFu, s3 = e4.w & 0x1FFFFu;
    unsigned h0 = (unsigned)__half_as_ushort(__hmul(__ushort_as_half((unsigned short)(e4.x >> 17)), __ushort_as_half(tabh[s0])));
    unsigned h1 = (unsigned)__half_as_ushort(__hmul(__ushort_as_half((unsigned short)(e4.y >> 17)), __ushort_as_half(tabh[s1])));
    unsigned h2 = (unsigned)__half_as_ushort(__hmul(__ushort_as_half((unsigned short)(e4.z >> 17)), __ushort_as_half(tabh[s2])));
    unsigned h3 = (unsigned)__half_as_ushort(__hmul(__ushort_as_half((unsigned short)(e4.w >> 17)), __ushort_as_half(tabh[s3])));
    uint4 o;
    o.x = (h0 << 17) | s0; o.y = (h1 << 17) | s1;
    o.z = (h2 << 17) | s2; o.w = (h3 << 17) | s3;
    *reinterpret_cast<uint4*>(eqf + i) = o;
}

// gather: one wave per node; 4 lane-groups of 16 handle 4 edges (a quad);
// edge record u32 = fp15 weight<<17 | src (CACHED load); lane loads u32 = 4
// biased-int8 dims; perm-magic dequant; hfma2. 32-edge main, 4-edge tail.
// Non-FINAL: quantize output row to int8+scale. FINAL: fused 4-way combine.
template <bool FINAL>
__global__ void __launch_bounds__(256) k_gather(const int* __restrict__ rowptr,
        const unsigned short* __restrict__ pdeg16,
        const unsigned* __restrict__ eq,
        const unsigned* __restrict__ xq, unsigned* __restrict__ yq,
        float* __restrict__ ys, const float* __restrict__ emb,
        const unsigned* __restrict__ y1q, const float* __restrict__ y1s,
        const float* __restrict__ y2s, const float* __restrict__ attnp,
        float* __restrict__ out0, float* __restrict__ acc) {
    int gt = blockIdx.x * 256 + threadIdx.x;   // grid = NN*64/256 = 25000 exact
    int nid = gt >> 6;                         // wave-uniform
    int lane = gt & 63;
    int g = lane >> 4;                         // edge slot 0..3 within quad
    int gi = lane & 15;                        // 4-dim chunk index
    int beg = __builtin_amdgcn_readfirstlane(rowptr[nid]);
    int pd  = __builtin_amdgcn_readfirstlane((int)pdeg16[nid]);
    int end = beg + pd;
    const unsigned* eqg = eq + g;
    U32H2 BIAS; BIAS.u = 0x64806480u;          // half2 {1152, 1152}
    __half2 z = __float2half2_rn(0.0f);
    __half2 pa0 = z, pa1 = z, pb0 = z, pb1 = z;

#define QE(J, A0, A1) { \
    unsigned eu = eqg[J]; \
    unsigned s = eu & 0x1FFFFu; \
    unsigned wu = eu >> 17; \
    U32H2 wd; wd.u = __builtin_amdgcn_perm(wu, wu, 0x01000100u); \
    unsigned ch = xq[(s << 4) | (unsigned)gi]; \
    U32H2 h0; h0.u = __builtin_amdgcn_perm(C64, ch, 0x04010400u); \
    U32H2 h1; h1.u = __builtin_amdgcn_perm(C64, ch, 0x04030402u); \
    A0 = __hfma2(wd.h, __hsub2(h0.h, BIAS.h), A0); \
    A1 = __hfma2(wd.h, __hsub2(h1.h, BIAS.h), A1); }

    int j = beg;
    int n32 = beg + (pd & ~31);
    for (; j < n32; j += 32) {
        QE(j,      pa0, pa1); QE(j + 4,  pb0, pb1);
        QE(j + 8,  pa0, pa1); QE(j + 12, pb0, pb1);
        QE(j + 16, pa0, pa1); QE(j + 20, pb0, pb1);
        QE(j + 24, pa0, pa1); QE(j + 28, pb0, pb1);
    }
    for (; j < end; j += 4) {                  // 4-edge tail (<=7 iters, uniform)
        QE(j, pa0, pa1);
    }
#undef QE

    float2 fa0 = __half22float2(pa0), fb0 = __half22float2(pb0);
    float2 fa1 = __half22float2(pa1), fb1 = __half22float2(pb1);
    float a0 = (fa0.x + fb0.x) * INV512;       // dim 4gi+0
    float a1 = (fa0.y + fb0.y) * INV512;       // dim 4gi+1
    float a2 = (fa1.x + fb1.x) * INV512;       // dim 4gi+2
    float a3 = (fa1.y + fb1.y) * INV512;       // dim 4gi+3
    a0 += __shfl_xor(a0, 16, 64); a0 += __shfl_xor(a0, 32, 64);
    a1 += __shfl_xor(a1, 16, 64); a1 += __shfl_xor(a1, 32, 64);
    a2 += __shfl_xor(a2, 16, 64); a2 += __shfl_xor(a2, 32, 64);
    a3 += __shfl_xor(a3, 16, 64); a3 += __shfl_xor(a3, 32, 64);
    if (lane < 16) {
        unsigned ri = (unsigned)(nid << 4) | (unsigned)gi;
        if (!FINAL) {
            float m = fmaxf(fmaxf(fabsf(a0), fabsf(a1)), fmaxf(fabsf(a2), fabsf(a3)));
            m = fmaxf(m, __shfl_xor(m, 1, 64));
            m = fmaxf(m, __shfl_xor(m, 2, 64));
            m = fmaxf(m, __shfl_xor(m, 4, 64));
            m = fmaxf(m, __shfl_xor(m, 8, 64));
            float inv = (m > 0.0f) ? 127.0f / m : 0.0f;
            int q0 = (int)rintf(a0 * inv) + 128;
            int q1 = (int)rintf(a1 * inv) + 128;
            int q2 = (int)rintf(a2 * inv) + 128;
            int q3 = (int)rintf(a3 * inv) + 128;
            unsigned u = (unsigned)(q0 & 0xFF) | ((unsigned)(q1 & 0xFF) << 8)
                       | ((unsigned)(q2 & 0xFF) << 16) | ((unsigned)(q3 & 0xFF) << 24);
            yq[ri] = u;
            if (gi == 0) ys[nid] = m * (1.0f / 127.0f);
        } else {
            float w0 = attnp[0], w1 = attnp[1], w2 = attnp[2], w3 = attnp[3];
            float4 e = reinterpret_cast<const float4*>(emb)[ri];
            float s1 = y1s[nid], s2 = y2s[nid];
            unsigned u1 = y1q[ri], u2 = xq[ri];         // xq == y2q
            U32H2 d10, d11, d20, d21;
            d10.u = __builtin_amdgcn_perm(C64, u1, 0x04010400u);
            d11.u = __builtin_amdgcn_perm(C64, u1, 0x04030402u);
            d20.u = __builtin_amdgcn_perm(C64, u2, 0x04010400u);
            d21.u = __builtin_amdgcn_perm(C64, u2, 0x04030402u);
            float2 p10 = __half22float2(__hsub2(d10.h, BIAS.h));
            float2 p11 = __half22float2(__hsub2(d11.h, BIAS.h));
            float2 p20 = __half22float2(__hsub2(d20.h, BIAS.h));
            float2 p21 = __half22float2(__hsub2(d21.h, BIAS.h));
            float4 r;
            r.x = w0 * e.x + w1 * (p10.x * s1) + w2 * (p20.x * s2) + w3 * a0;
            r.y = w0 * e.y + w1 * (p10.y * s1) + w2 * (p20.y * s2) + w3 * a1;
            r.z = w0 * e.z + w1 * (p11.x * s1) + w2 * (p21.x * s2) + w3 * a2;
            r.w = w0 * e.w + w1 * (p11.y * s1) + w2 * (p21.y * s2) + w3 * a3;
            reinterpret_cast<float4*>(out0)[ri] = e;
            reinterpret_cast<float4*>(acc)[ri] = r;
        }
    }
}

extern "C" void kernel_launch(void* const* d_in, const int* in_sizes, int n_in,
                              void* d_out, int out_size, void* d_ws, size_t ws_size,
                              hipStream_t stream) {
    const float* emb   = (const float*)d_in[0];
    const float* attw  = (const float*)d_in[1];
    const float* scale = (const float*)d_in[2];
    const float* attr  = (const float*)d_in[3];
    const int*   ei    = (const int*)d_in[4];
    const int* src = ei;
    const int* dst = ei + NE;

    float* out0 = (float*)d_out;
    float* acc  = out0 + (size_t)NN * ED;

    // workspace (~58.5 MB). part (27.3MB) dead after k_build -> aliased by
    // the quantized x/y buffers (3 x 6.8MB).
    const size_t SLOTS  = (size_t)NBUCK * CAP;    // 3,411,968 (part)
    const size_t PSLOTS = (size_t)NBUCK * PCAP;   // 3,713,024 (estat/eqf)
    char* ws = (char*)d_ws;
    size_t off = 0;
    float*  attn   = (float*)(ws + off); off += 256;
    int*    gcur   = (int*)(ws + off);   off += 1024;
    float*  dinvf  = (float*)(ws + off); off += ((size_t)NN * 4 + 255) & ~(size_t)255;
    int*    rowptr = (int*)(ws + off);   off += ((size_t)NN * 4 + 255) & ~(size_t)255;
    unsigned short* pdeg16 = (unsigned short*)(ws + off); off += ((size_t)NN * 2 + 255) & ~(size_t)255;
    unsigned short* tabh   = (unsigned short*)(ws + off); off += (size_t)131072 * 2;  // 2^17 entries
    char*   partc  = ws + off;           off += SLOTS * 8;
    unsigned long long* part = (unsigned long long*)partc;
    unsigned* estat = (unsigned*)(ws + off); off += PSLOTS * 4;
    unsigned* eqf   = (unsigned*)(ws + off); off += PSLOTS * 4;
    // aliases into dead part region (written only after k_build):
    const size_t QROW = (size_t)NN * ED;          // 6,400,000 bytes (u8)
    const size_t SSZ  = ((size_t)NN * 4 + 383) & ~(size_t)255;   // 400,384
    unsigned* xq0 = (unsigned*)(partc);
    float*    xs0 = (float*)(partc + QROW);
    unsigned* y1q = (unsigned*)(partc + QROW + SSZ);
    float*    y1s = (float*)(partc + 2 * QROW + SSZ);
    unsigned* y2q = (unsigned*)(partc + 2 * QROW + 2 * SSZ);
    float*    y2s = (float*)(partc + 3 * QROW + 2 * SSZ);

    const int QB = (NN * 16) / 256;            // 6250 exact (k_prep)
    const int GB = (NN * ED) / 256;            // 25000 exact
    const int PB = (NE + CHUNK - 1) / CHUNK;   // 391
    const int NB = (NN + 255) / 256;           // 391 (k_tab)
    const int FB = (int)(PSLOTS / 4 / 256);    // 3626 exact (k_fold)

    k_init<<<1, 256, 0, stream>>>(attw, attn, gcur);
    k_part<<<PB, PTH, 0, stream>>>(src, dst, attr, scale, gcur, part);
    k_build<<<NBUCK, 1024, 0, stream>>>(gcur, part, rowptr, pdeg16, dinvf, estat);
    // part dead from here; quantized buffers alias it
    k_prep<<<QB, 256, 0, stream>>>(emb, xq0, xs0);

    k_tab<<<NB, 256, 0, stream>>>(dinvf, xs0, tabh);
    k_fold<<<FB, 256, 0, stream>>>(estat, eqf, tabh);
    k_gather<false><<<GB, 256, 0, stream>>>(rowptr, pdeg16, eqf, xq0, y1q, y1s,
        nullptr, nullptr, nullptr, nullptr, nullptr, nullptr, nullptr);

    k_tab<<<NB, 256, 0, stream>>>(dinvf, y1s, tabh);
    k_fold<<<FB, 256, 0, stream>>>(estat, eqf, tabh);
    k_gather<false><<<GB, 256, 0, stream>>>(rowptr, pdeg16, eqf, y1q, y2q, y2s,
        nullptr, nullptr, nullptr, nullptr, nullptr, nullptr, nullptr);

    k_tab<<<NB, 256, 0, stream>>>(dinvf, y2s, tabh);
    k_fold<<<FB, 256, 0, stream>>>(estat, eqf, tabh);
    k_gather<true><<<GB, 256, 0, stream>>>(rowptr, pdeg16, eqf, y2q, nullptr, nullptr,
        emb, y1q, y1s, y2s, attn, out0, acc);
}

// Round 15
// 238.372 us; speedup vs baseline: 1.4680x; 1.2130x over previous
//
#include <hip/hip_runtime.h>
#include <hip/hip_fp16.h>

#define NN 100000          // N_NODES
#define ED 64              // EMB_DIM
#define NE 3200000         // N_EDGES
#define BSH 9              // log2 nodes per bucket
#define BNODES 512
#define NBUCK 196          // ceil(NN/BNODES)
#define CAP 17408          // slots per bucket (mean 16327, +8 sigma), mult of 64
#define PCAP 18944         // CAP + 512*3 pad headroom, mult of 64
#define CHUNK 8192
#define PTH 512

union U32H2 { unsigned u; __half2 h; };
__device__ __forceinline__ float h2lo(unsigned u) { U32H2 c; c.u = u; return __low2float(c.h); }
__device__ __forceinline__ float h2hi(unsigned u) { U32H2 c; c.u = u; return __high2float(c.h); }

// softmax(attn weights) + init bucket cursors gcur[b] = b*CAP
__global__ void k_init(const float* __restrict__ w, float* __restrict__ attn,
                       int* __restrict__ gcur) {
    int t = threadIdx.x;
    if (t < NBUCK) gcur[t] = t * CAP;
    if (t == 0) {
        float m = fmaxf(fmaxf(w[0], w[1]), fmaxf(w[2], w[3]));
        float e0 = expf(w[0] - m), e1 = expf(w[1] - m), e2 = expf(w[2] - m), e3 = expf(w[3] - m);
        float s = e0 + e1 + e2 + e3;
        attn[0] = e0 / s; attn[1] = e1 / s; attn[2] = e2 / s; attn[3] = e3 / s;
    }
}

// pass 1: partition edges into fixed-CAP dst-buckets. 4 edges/thread.
// entry u64 = eattr fp16 <<32 | dl 9b <<17 | src 17b, eattr = exp(scale*attr)
__global__ void __launch_bounds__(PTH) k_part(const int* __restrict__ src,
        const int* __restrict__ dst, const float* __restrict__ attr,
        const float* __restrict__ scale,
        int* __restrict__ gcur, unsigned long long* __restrict__ part) {
    __shared__ unsigned long long stage[CHUNK];   // 64 KiB
    __shared__ int hist[NBUCK];
    __shared__ int lstart[NBUCK + 1];
    __shared__ int gbase[NBUCK];
    __shared__ unsigned char bkof[CHUNK];         // 8 KiB
    const int tid = threadIdx.x;
    const int base = blockIdx.x * CHUNK;
    const int n = min(CHUNK, NE - base);
    for (int i = tid; i < NBUCK; i += PTH) hist[i] = 0;
    __syncthreads();
    for (int i = tid * 4; i < n; i += PTH * 4) {
        int4 d4 = *reinterpret_cast<const int4*>(dst + base + i);
        atomicAdd(&hist[d4.x >> BSH], 1); atomicAdd(&hist[d4.y >> BSH], 1);
        atomicAdd(&hist[d4.z >> BSH], 1); atomicAdd(&hist[d4.w >> BSH], 1);
    }
    __syncthreads();
    if (tid < 64) {                                // exclusive scan of hist
        int carry = 0;
        #pragma unroll
        for (int g = 0; g < 4; ++g) {
            int b = g * 64 + tid;
            int v = (b < NBUCK) ? hist[b] : 0;
            int s = v;
            #pragma unroll
            for (int o = 1; o < 64; o <<= 1) { int t = __shfl_up(s, o, 64); if (tid >= o) s += t; }
            if (b < NBUCK) lstart[b] = carry + s - v;
            carry += __shfl(s, 63, 64);
        }
        if (tid == 0) lstart[NBUCK] = n;
    }
    __syncthreads();
    for (int b = tid; b < NBUCK; b += PTH) {
        int cnt = lstart[b + 1] - lstart[b];
        gbase[b] = atomicAdd(&gcur[b], cnt);
        hist[b] = lstart[b];
    }
    __syncthreads();
    const float sc = scale[0];
    for (int i = tid * 4; i < n; i += PTH * 4) {
        int4 s4 = *reinterpret_cast<const int4*>(src + base + i);
        int4 d4 = *reinterpret_cast<const int4*>(dst + base + i);
        float4 a4 = *reinterpret_cast<const float4*>(attr + base + i);
        #pragma unroll
        for (int k = 0; k < 4; ++k) {
            int s = (k == 0) ? s4.x : (k == 1) ? s4.y : (k == 2) ? s4.z : s4.w;
            int d = (k == 0) ? d4.x : (k == 1) ? d4.y : (k == 2) ? d4.z : d4.w;
            float a = (k == 0) ? a4.x : (k == 1) ? a4.y : (k == 2) ? a4.z : a4.w;
            unsigned short ea = __half_as_ushort(__float2half(expf(sc * a)));
            int bk = d >> BSH;
            int p = atomicAdd(&hist[bk], 1);
            stage[p] = ((unsigned long long)ea << 32)
                     | (unsigned)(s | ((d & (BNODES - 1)) << 17));
            bkof[p] = (unsigned char)bk;
        }
    }
    __syncthreads();
    for (int i = tid; i < n; i += PTH) {
        int bk = bkof[i];
        part[(size_t)gbase[bk] + (i - lstart[bk])] = stage[i];
    }
}

// merged build: per-bucket histogram -> padded scan -> placement.
// eq[p] = ( fp15(dinv[dst]*eattr) << 17 ) | src   (dinv[src] applied by k_fold)
__global__ void __launch_bounds__(1024) k_build(const int* __restrict__ gcur,
        const unsigned long long* __restrict__ part,
        int* __restrict__ rowptr, unsigned short* __restrict__ pdeg16,
        float* __restrict__ dinvf, unsigned* __restrict__ eq) {
    __shared__ int deg[BNODES];
    __shared__ int cur[BNODES];
    __shared__ float dli[BNODES];
    __shared__ int wsum[8];
    const int b = blockIdx.x, tid = threadIdx.x;
    const int rs = b * CAP, re = gcur[b];
    if (tid < BNODES) deg[tid] = 0;
    __syncthreads();
    for (int j = rs + tid; j < re; j += 1024) {
        unsigned lo = (unsigned)part[j];
        atomicAdd(&deg[(lo >> 17) & (BNODES - 1)], 1);
    }
    __syncthreads();
    int start = 0, pd = 0, d = 0;
    if (tid < BNODES) {
        const int lane = tid & 63, wv = tid >> 6;
        d = deg[tid];
        pd = (d + 3) & ~3;
        int x = pd;
        #pragma unroll
        for (int o = 1; o < 64; o <<= 1) { int t = __shfl_up(x, o, 64); if (lane >= o) x += t; }
        if (lane == 63) wsum[wv] = x;
        __syncthreads();
        if (tid < 8) {
            int orig = wsum[tid]; int t = orig;
            #pragma unroll
            for (int o = 1; o < 8; o <<= 1) { int u = __shfl_up(t, o, 64); if (tid >= o) t += u; }
            wsum[tid] = t - orig;
        }
        __syncthreads();
        int node = b * BNODES + tid;
        start = b * PCAP + wsum[wv] + (x - pd);
        cur[tid] = start;
        float dv = (d > 0) ? rsqrtf((float)d) : 0.0f;
        dli[tid] = dv;
        if (node < NN) {
            rowptr[node] = start;
            pdeg16[node] = (unsigned short)pd;
            dinvf[node] = dv;
        }
    } else {
        __syncthreads();
        __syncthreads();
    }
    __syncthreads();
    // placement pass
    for (int j = rs + tid; j < re; j += 1024) {
        unsigned long long v = part[j];
        unsigned lo = (unsigned)v;
        unsigned s = lo & 0x1FFFFu;
        int dl = (lo >> 17) & (BNODES - 1);
        float ea = __half2float(__ushort_as_half((unsigned short)(v >> 32)));
        float w = dli[dl] * ea;                    // >= 0, fp16 sign bit = 0
        unsigned hw = (unsigned)__half_as_ushort(__float2half(w));
        int p = atomicAdd(&cur[dl], 1);
        eq[p] = (hw << 17) | s;
    }
    __syncthreads();
    if (tid < BNODES) {                            // zero the <=3 pad slots per row
        int fin = start + pd;
        for (int p = cur[tid]; p < fin; ++p) eq[p] = 0u;
    }
}

// single fold (in-place): eq[i].w *= dinvf[src]. Makes the weight fully static.
// Processes ALL PSLOTS slots; garbage srcs memory-safe (dinvf padded to 2^17).
__global__ void k_fold(unsigned* __restrict__ eq, const float* __restrict__ dinvf) {
    int i = (blockIdx.x * 256 + threadIdx.x) * 4;   // grid 3626 exact over PSLOTS
    uint4 e4 = *reinterpret_cast<const uint4*>(eq + i);
    unsigned s0 = e4.x & 0x1FFFFu, s1 = e4.y & 0x1FFFFu;
    unsigned s2 = e4.z & 0x1FFFFu, s3 = e4.w & 0x1FFFFu;
    float w0 = __half2float(__ushort_as_half((unsigned short)(e4.x >> 17))) * dinvf[s0];
    float w1 = __half2float(__ushort_as_half((unsigned short)(e4.y >> 17))) * dinvf[s1];
    float w2 = __half2float(__ushort_as_half((unsigned short)(e4.z >> 17))) * dinvf[s2];
    float w3 = __half2float(__ushort_as_half((unsigned short)(e4.w >> 17))) * dinvf[s3];
    uint4 o;
    o.x = ((unsigned)__half_as_ushort(__float2half(w0)) << 17) | s0;
    o.y = ((unsigned)__half_as_ushort(__float2half(w1)) << 17) | s1;
    o.z = ((unsigned)__half_as_ushort(__float2half(w2)) << 17) | s2;
    o.w = ((unsigned)__half_as_ushort(__float2half(w3)) << 17) | s3;
    *reinterpret_cast<uint4*>(eq + i) = o;
}

// x0 = fp16(emb). grid = NN*ED/4/256 = 6250 exact
__global__ void k_prep(const float* __restrict__ emb, unsigned short* __restrict__ x0) {
    int i = blockIdx.x * 256 + threadIdx.x;
    float4 e = reinterpret_cast<const float4*>(emb)[i];
    ushort4 u;
    u.x = __half_as_ushort(__float2half(e.x));
    u.y = __half_as_ushort(__float2half(e.y));
    u.z = __half_as_ushort(__float2half(e.z));
    u.w = __half_as_ushort(__float2half(e.w));
    reinterpret_cast<ushort4*>(x0)[i] = u;
}

// gather: one wave per node; 4 lane-groups of 16 handle 4 edges (a quad);
// edge record u32 = fp15 static weight <<17 | src (1 load); lane loads
// uint2 = 4 fp16 dims; hfma2. 32-edge main loop + 16/8/4 tail cascade.
// Non-FINAL: write fp16 row. FINAL: fused 4-way combine epilogue.
template <bool FINAL>
__global__ void __launch_bounds__(256) k_gather(const int* __restrict__ rowptr,
        const unsigned short* __restrict__ pdeg16,
        const unsigned* __restrict__ eq,
        const unsigned short* __restrict__ x, unsigned short* __restrict__ y,
        const unsigned short* __restrict__ y1, const float* __restrict__ emb,
        const float* __restrict__ attnp, float* __restrict__ out0,
        float* __restrict__ acc) {
    int gt = blockIdx.x * 256 + threadIdx.x;   // grid = NN*64/256 = 25000 exact
    int nid = gt >> 6;                         // wave-uniform
    int lane = gt & 63;
    int g = lane >> 4;                         // edge slot 0..3 within quad
    int gi = lane & 15;                        // 4-dim chunk index
    int beg = __builtin_amdgcn_readfirstlane(rowptr[nid]);
    int pd  = __builtin_amdgcn_readfirstlane((int)pdeg16[nid]);
    const unsigned* eqg = eq + g;
    const uint2* xv = reinterpret_cast<const uint2*>(x);
    __half2 z = __float2half2_rn(0.0f);
    __half2 pa0 = z, pa1 = z, pb0 = z, pb1 = z;

#define QE(J, A0, A1) { \
    unsigned eu = eqg[J]; \
    unsigned s = eu & 0x1FFFFu; \
    unsigned wu = eu >> 17; \
    U32H2 wd; wd.u = __builtin_amdgcn_perm(wu, wu, 0x01000100u); \
    uint2 u = xv[(s << 4) | (unsigned)gi]; \
    U32H2 ux, uy; ux.u = u.x; uy.u = u.y; \
    A0 = __hfma2(wd.h, ux.h, A0); \
    A1 = __hfma2(wd.h, uy.h, A1); }

    int j = beg;
    int n32 = beg + (pd & ~31);
    for (; j < n32; j += 32) {
        QE(j,      pa0, pa1); QE(j + 4,  pb0, pb1);
        QE(j + 8,  pa0, pa1); QE(j + 12, pb0, pb1);
        QE(j + 16, pa0, pa1); QE(j + 20, pb0, pb1);
        QE(j + 24, pa0, pa1); QE(j + 28, pb0, pb1);
    }
    if (pd & 16) {                             // 16-edge tail step (4 quads)
        QE(j, pa0, pa1); QE(j + 4, pb0, pb1);
        QE(j + 8, pa0, pa1); QE(j + 12, pb0, pb1);
        j += 16;
    }
    if (pd & 8) {                              // 8-edge tail step (2 quads)
        QE(j, pa0, pa1); QE(j + 4, pb0, pb1);
        j += 8;
    }
    if (pd & 4) {                              // 4-edge tail step (1 quad)
        QE(j, pa0, pa1);
    }
#undef QE

    float2 fa0 = __half22float2(pa0), fb0 = __half22float2(pb0);
    float2 fa1 = __half22float2(pa1), fb1 = __half22float2(pb1);
    float a0 = fa0.x + fb0.x;                  // dim 4gi+0
    float a1 = fa0.y + fb0.y;                  // dim 4gi+1
    float a2 = fa1.x + fb1.x;                  // dim 4gi+2
    float a3 = fa1.y + fb1.y;                  // dim 4gi+3
    a0 += __shfl_xor(a0, 16, 64); a0 += __shfl_xor(a0, 32, 64);
    a1 += __shfl_xor(a1, 16, 64); a1 += __shfl_xor(a1, 32, 64);
    a2 += __shfl_xor(a2, 16, 64); a2 += __shfl_xor(a2, 32, 64);
    a3 += __shfl_xor(a3, 16, 64); a3 += __shfl_xor(a3, 32, 64);
    if (lane < 16) {
        unsigned ri = (unsigned)(nid << 4) | (unsigned)gi;
        if (!FINAL) {
            U32H2 o01, o23;
            o01.h = __floats2half2_rn(a0, a1);
            o23.h = __floats2half2_rn(a2, a3);
            uint2 o; o.x = o01.u; o.y = o23.u;
            reinterpret_cast<uint2*>(y)[ri] = o;
        } else {
            float w0 = attnp[0], w1 = attnp[1], w2 = attnp[2], w3 = attnp[3];
            float4 e = reinterpret_cast<const float4*>(emb)[ri];
            uint2 v1 = reinterpret_cast<const uint2*>(y1)[ri];
            uint2 v2 = xv[ri];                 // y2 row of this node
            float4 r;
            r.x = w0 * e.x + w1 * h2lo(v1.x) + w2 * h2lo(v2.x) + w3 * a0;
            r.y = w0 * e.y + w1 * h2hi(v1.x) + w2 * h2hi(v2.x) + w3 * a1;
            r.z = w0 * e.z + w1 * h2lo(v1.y) + w2 * h2lo(v2.y) + w3 * a2;
            r.w = w0 * e.w + w1 * h2hi(v1.y) + w2 * h2hi(v2.y) + w3 * a3;
            reinterpret_cast<float4*>(out0)[ri] = e;
            reinterpret_cast<float4*>(acc)[ri] = r;
        }
    }
}

extern "C" void kernel_launch(void* const* d_in, const int* in_sizes, int n_in,
                              void* d_out, int out_size, void* d_ws, size_t ws_size,
                              hipStream_t stream) {
    const float* emb   = (const float*)d_in[0];
    const float* attw  = (const float*)d_in[1];
    const float* scale = (const float*)d_in[2];
    const float* attr  = (const float*)d_in[3];
    const int*   ei    = (const int*)d_in[4];
    const int* src = ei;
    const int* dst = ei + NE;

    float* out0 = (float*)d_out;
    float* acc  = out0 + (size_t)NN * ED;

    // workspace (~56 MB). part (27.3MB) dead after k_build -> aliased by
    // the fp16 x0/y1 buffers (2 x 12.8MB).
    const size_t SLOTS  = (size_t)NBUCK * CAP;    // 3,411,968 (part)
    const size_t PSLOTS = (size_t)NBUCK * PCAP;   // 3,713,024 (eq)
    char* ws = (char*)d_ws;
    size_t off = 0;
    float*  attn   = (float*)(ws + off); off += 256;
    int*    gcur   = (int*)(ws + off);   off += 1024;
    float*  dinvf  = (float*)(ws + off); off += (size_t)131072 * 4;   // padded to 2^17
    int*    rowptr = (int*)(ws + off);   off += ((size_t)NN * 4 + 255) & ~(size_t)255;
    unsigned short* pdeg16 = (unsigned short*)(ws + off); off += ((size_t)NN * 2 + 255) & ~(size_t)255;
    char*   partc  = ws + off;           off += SLOTS * 8;
    unsigned long long* part = (unsigned long long*)partc;
    unsigned* eq   = (unsigned*)(ws + off); off += PSLOTS * 4;
    unsigned short* y2 = (unsigned short*)(ws + off); off += (size_t)NN * ED * 2;
    // aliases into dead part region (written only after k_build):
    unsigned short* x0 = (unsigned short*)partc;
    unsigned short* y1 = (unsigned short*)partc + (size_t)NN * ED;

    const int VB = (NN * ED / 4) / 256;        // 6250 exact (k_prep)
    const int GB = (NN * ED) / 256;            // 25000 exact
    const int PB = (NE + CHUNK - 1) / CHUNK;   // 391
    const int FB = (int)(PSLOTS / 4 / 256);    // 3626 exact (k_fold)

    k_init<<<1, 256, 0, stream>>>(attw, attn, gcur);
    k_part<<<PB, PTH, 0, stream>>>(src, dst, attr, scale, gcur, part);
    k_build<<<NBUCK, 1024, 0, stream>>>(gcur, part, rowptr, pdeg16, dinvf, eq);
    k_fold<<<FB, 256, 0, stream>>>(eq, dinvf);
    // part dead from here; x0/y1 alias it
    k_prep<<<VB, 256, 0, stream>>>(emb, x0);

    k_gather<false><<<GB, 256, 0, stream>>>(rowptr, pdeg16, eq, x0, y1,
        nullptr, nullptr, nullptr, nullptr, nullptr);
    k_gather<false><<<GB, 256, 0, stream>>>(rowptr, pdeg16, eq, y1, y2,
        nullptr, nullptr, nullptr, nullptr, nullptr);
    k_gather<true><<<GB, 256, 0, stream>>>(rowptr, pdeg16, eq, y2, nullptr,
        y1, emb, attn, out0, acc);
}

// Round 16
// 226.730 us; speedup vs baseline: 1.5433x; 1.0513x over previous
//
#include <hip/hip_runtime.h>
#include <hip/hip_fp16.h>

#define NN 100000          // N_NODES
#define ED 64              // EMB_DIM
#define NE 3200000         // N_EDGES
#define BSH 9              // log2 nodes per bucket
#define BNODES 512
#define NBUCK 196          // ceil(NN/BNODES)
#define CAP 17408          // slots per bucket (mean 16327, +8 sigma), mult of 64
#define PCAP 18944         // CAP + 512*3 pad headroom, mult of 64
#define CHUNK 8192
#define PTH 512

union U32H2 { unsigned u; __half2 h; };
__device__ __forceinline__ float h2lo(unsigned u) { U32H2 c; c.u = u; return __low2float(c.h); }
__device__ __forceinline__ float h2hi(unsigned u) { U32H2 c; c.u = u; return __high2float(c.h); }

// softmax(attn weights) + init bucket cursors gcur[b] = b*CAP
__global__ void k_init(const float* __restrict__ w, float* __restrict__ attn,
                       int* __restrict__ gcur) {
    int t = threadIdx.x;
    if (t < NBUCK) gcur[t] = t * CAP;
    if (t == 0) {
        float m = fmaxf(fmaxf(w[0], w[1]), fmaxf(w[2], w[3]));
        float e0 = expf(w[0] - m), e1 = expf(w[1] - m), e2 = expf(w[2] - m), e3 = expf(w[3] - m);
        float s = e0 + e1 + e2 + e3;
        attn[0] = e0 / s; attn[1] = e1 / s; attn[2] = e2 / s; attn[3] = e3 / s;
    }
}

// pass 1: partition edges into fixed-CAP dst-buckets. 4 edges/thread.
// entry u64 = eattr fp16 <<32 | dl 9b <<17 | src 17b, eattr = exp(scale*attr)
__global__ void __launch_bounds__(PTH) k_part(const int* __restrict__ src,
        const int* __restrict__ dst, const float* __restrict__ attr,
        const float* __restrict__ scale,
        int* __restrict__ gcur, unsigned long long* __restrict__ part) {
    __shared__ unsigned long long stage[CHUNK];   // 64 KiB
    __shared__ int hist[NBUCK];
    __shared__ int lstart[NBUCK + 1];
    __shared__ int gbase[NBUCK];
    __shared__ unsigned char bkof[CHUNK];         // 8 KiB
    const int tid = threadIdx.x;
    const int base = blockIdx.x * CHUNK;
    const int n = min(CHUNK, NE - base);
    for (int i = tid; i < NBUCK; i += PTH) hist[i] = 0;
    __syncthreads();
    for (int i = tid * 4; i < n; i += PTH * 4) {
        int4 d4 = *reinterpret_cast<const int4*>(dst + base + i);
        atomicAdd(&hist[d4.x >> BSH], 1); atomicAdd(&hist[d4.y >> BSH], 1);
        atomicAdd(&hist[d4.z >> BSH], 1); atomicAdd(&hist[d4.w >> BSH], 1);
    }
    __syncthreads();
    if (tid < 64) {                                // exclusive scan of hist
        int carry = 0;
        #pragma unroll
        for (int g = 0; g < 4; ++g) {
            int b = g * 64 + tid;
            int v = (b < NBUCK) ? hist[b] : 0;
            int s = v;
            #pragma unroll
            for (int o = 1; o < 64; o <<= 1) { int t = __shfl_up(s, o, 64); if (tid >= o) s += t; }
            if (b < NBUCK) lstart[b] = carry + s - v;
            carry += __shfl(s, 63, 64);
        }
        if (tid == 0) lstart[NBUCK] = n;
    }
    __syncthreads();
    for (int b = tid; b < NBUCK; b += PTH) {
        int cnt = lstart[b + 1] - lstart[b];
        gbase[b] = atomicAdd(&gcur[b], cnt);
        hist[b] = lstart[b];
    }
    __syncthreads();
    const float sc = scale[0];
    for (int i = tid * 4; i < n; i += PTH * 4) {
        int4 s4 = *reinterpret_cast<const int4*>(src + base + i);
        int4 d4 = *reinterpret_cast<const int4*>(dst + base + i);
        float4 a4 = *reinterpret_cast<const float4*>(attr + base + i);
        #pragma unroll
        for (int k = 0; k < 4; ++k) {
            int s = (k == 0) ? s4.x : (k == 1) ? s4.y : (k == 2) ? s4.z : s4.w;
            int d = (k == 0) ? d4.x : (k == 1) ? d4.y : (k == 2) ? d4.z : d4.w;
            float a = (k == 0) ? a4.x : (k == 1) ? a4.y : (k == 2) ? a4.z : a4.w;
            unsigned short ea = __half_as_ushort(__float2half(expf(sc * a)));
            int bk = d >> BSH;
            int p = atomicAdd(&hist[bk], 1);
            stage[p] = ((unsigned long long)ea << 32)
                     | (unsigned)(s | ((d & (BNODES - 1)) << 17));
            bkof[p] = (unsigned char)bk;
        }
    }
    __syncthreads();
    for (int i = tid; i < n; i += PTH) {
        int bk = bkof[i];
        part[(size_t)gbase[bk] + (i - lstart[bk])] = stage[i];
    }
}

// merged build: per-bucket histogram -> padded scan -> placement.
// eq[p] = ( fp15(dinv[dst]*eattr) << 17 ) | src  — COMPLETE static weight
// (dinv[src] is folded into the x operand, not the weight). Also sqdeg[n].
__global__ void __launch_bounds__(1024) k_build(const int* __restrict__ gcur,
        const unsigned long long* __restrict__ part,
        int* __restrict__ rowptr, unsigned short* __restrict__ pdeg16,
        float* __restrict__ dinvf, float* __restrict__ sqdeg,
        unsigned* __restrict__ eq) {
    __shared__ int deg[BNODES];
    __shared__ int cur[BNODES];
    __shared__ float dli[BNODES];
    __shared__ int wsum[8];
    const int b = blockIdx.x, tid = threadIdx.x;
    const int rs = b * CAP, re = gcur[b];
    if (tid < BNODES) deg[tid] = 0;
    __syncthreads();
    for (int j = rs + tid; j < re; j += 1024) {
        unsigned lo = (unsigned)part[j];
        atomicAdd(&deg[(lo >> 17) & (BNODES - 1)], 1);
    }
    __syncthreads();
    int start = 0, pd = 0, d = 0;
    if (tid < BNODES) {
        const int lane = tid & 63, wv = tid >> 6;
        d = deg[tid];
        pd = (d + 3) & ~3;
        int x = pd;
        #pragma unroll
        for (int o = 1; o < 64; o <<= 1) { int t = __shfl_up(x, o, 64); if (lane >= o) x += t; }
        if (lane == 63) wsum[wv] = x;
        __syncthreads();
        if (tid < 8) {
            int orig = wsum[tid]; int t = orig;
            #pragma unroll
            for (int o = 1; o < 8; o <<= 1) { int u = __shfl_up(t, o, 64); if (tid >= o) t += u; }
            wsum[tid] = t - orig;
        }
        __syncthreads();
        int node = b * BNODES + tid;
        start = b * PCAP + wsum[wv] + (x - pd);
        cur[tid] = start;
        float dv = (d > 0) ? rsqrtf((float)d) : 0.0f;
        dli[tid] = dv;
        if (node < NN) {
            rowptr[node] = start;
            pdeg16[node] = (unsigned short)pd;
            dinvf[node] = dv;
            sqdeg[node] = (d > 0) ? sqrtf((float)d) : 0.0f;
        }
    } else {
        __syncthreads();
        __syncthreads();
    }
    __syncthreads();
    // placement pass
    for (int j = rs + tid; j < re; j += 1024) {
        unsigned long long v = part[j];
        unsigned lo = (unsigned)v;
        unsigned s = lo & 0x1FFFFu;
        int dl = (lo >> 17) & (BNODES - 1);
        float ea = __half2float(__ushort_as_half((unsigned short)(v >> 32)));
        float w = dli[dl] * ea;                    // >= 0, fp16 sign bit = 0
        unsigned hw = (unsigned)__half_as_ushort(__float2half(w));
        int p = atomicAdd(&cur[dl], 1);
        eq[p] = (hw << 17) | s;
    }
    __syncthreads();
    if (tid < BNODES) {                            // zero the <=3 pad slots per row
        int fin = start + pd;
        for (int p = cur[tid]; p < fin; ++p) eq[p] = 0u;
    }
}

// x0' = fp16( dinv[row] * emb ). grid = NN*ED/4/256 = 6250 exact
__global__ void k_prep(const float* __restrict__ emb, const float* __restrict__ dinvf,
                       unsigned short* __restrict__ x0) {
    int i = blockIdx.x * 256 + threadIdx.x;
    float dv = dinvf[i >> 4];
    float4 e = reinterpret_cast<const float4*>(emb)[i];
    ushort4 u;
    u.x = __half_as_ushort(__float2half(e.x * dv));
    u.y = __half_as_ushort(__float2half(e.y * dv));
    u.z = __half_as_ushort(__float2half(e.z * dv));
    u.w = __half_as_ushort(__float2half(e.w * dv));
    reinterpret_cast<ushort4*>(x0)[i] = u;
}

// gather: one wave per node; 4 lane-groups of 16 handle 4 edges (a quad);
// edge record u32 = fp15 static weight <<17 | src (1 load); lane loads
// uint2 = 4 fp16 dims of x' (= dinv-prescaled rows); hfma2.
// 32-edge main loop + 16/8/4 tail cascade.
// Non-FINAL: write y' = dinv[nid]*sum as fp16. FINAL: fused 4-way combine,
// unscaling y1'/y2' by sqdeg[nid].
template <bool FINAL>
__global__ void __launch_bounds__(256) k_gather(const int* __restrict__ rowptr,
        const unsigned short* __restrict__ pdeg16,
        const unsigned* __restrict__ eq,
        const float* __restrict__ dinvf, const float* __restrict__ sqdeg,
        const unsigned short* __restrict__ x, unsigned short* __restrict__ y,
        const unsigned short* __restrict__ y1, const float* __restrict__ emb,
        const float* __restrict__ attnp, float* __restrict__ out0,
        float* __restrict__ acc) {
    int gt = blockIdx.x * 256 + threadIdx.x;   // grid = NN*64/256 = 25000 exact
    int nid = gt >> 6;                         // wave-uniform
    int lane = gt & 63;
    int g = lane >> 4;                         // edge slot 0..3 within quad
    int gi = lane & 15;                        // 4-dim chunk index
    int beg = __builtin_amdgcn_readfirstlane(rowptr[nid]);
    int pd  = __builtin_amdgcn_readfirstlane((int)pdeg16[nid]);
    const unsigned* eqg = eq + g;
    const uint2* xv = reinterpret_cast<const uint2*>(x);
    __half2 z = __float2half2_rn(0.0f);
    __half2 pa0 = z, pa1 = z, pb0 = z, pb1 = z;

#define QE(J, A0, A1) { \
    unsigned eu = eqg[J]; \
    unsigned s = eu & 0x1FFFFu; \
    unsigned wu = eu >> 17; \
    U32H2 wd; wd.u = __builtin_amdgcn_perm(wu, wu, 0x01000100u); \
    uint2 u = xv[(s << 4) | (unsigned)gi]; \
    U32H2 ux, uy; ux.u = u.x; uy.u = u.y; \
    A0 = __hfma2(wd.h, ux.h, A0); \
    A1 = __hfma2(wd.h, uy.h, A1); }

    int j = beg;
    int n32 = beg + (pd & ~31);
    for (; j < n32; j += 32) {
        QE(j,      pa0, pa1); QE(j + 4,  pb0, pb1);
        QE(j + 8,  pa0, pa1); QE(j + 12, pb0, pb1);
        QE(j + 16, pa0, pa1); QE(j + 20, pb0, pb1);
        QE(j + 24, pa0, pa1); QE(j + 28, pb0, pb1);
    }
    if (pd & 16) {                             // 16-edge tail step (4 quads)
        QE(j, pa0, pa1); QE(j + 4, pb0, pb1);
        QE(j + 8, pa0, pa1); QE(j + 12, pb0, pb1);
        j += 16;
    }
    if (pd & 8) {                              // 8-edge tail step (2 quads)
        QE(j, pa0, pa1); QE(j + 4, pb0, pb1);
        j += 8;
    }
    if (pd & 4) {                              // 4-edge tail step (1 quad)
        QE(j, pa0, pa1);
    }
#undef QE

    float2 fa0 = __half22float2(pa0), fb0 = __half22float2(pb0);
    float2 fa1 = __half22float2(pa1), fb1 = __half22float2(pb1);
    float a0 = fa0.x + fb0.x;                  // dim 4gi+0
    float a1 = fa0.y + fb0.y;                  // dim 4gi+1
    float a2 = fa1.x + fb1.x;                  // dim 4gi+2
    float a3 = fa1.y + fb1.y;                  // dim 4gi+3
    a0 += __shfl_xor(a0, 16, 64); a0 += __shfl_xor(a0, 32, 64);
    a1 += __shfl_xor(a1, 16, 64); a1 += __shfl_xor(a1, 32, 64);
    a2 += __shfl_xor(a2, 16, 64); a2 += __shfl_xor(a2, 32, 64);
    a3 += __shfl_xor(a3, 16, 64); a3 += __shfl_xor(a3, 32, 64);
    if (lane < 16) {
        unsigned ri = (unsigned)(nid << 4) | (unsigned)gi;
        if (!FINAL) {
            float dv = dinvf[nid];             // self-scale the output row
            U32H2 o01, o23;
            o01.h = __floats2half2_rn(a0 * dv, a1 * dv);
            o23.h = __floats2half2_rn(a2 * dv, a3 * dv);
            uint2 o; o.x = o01.u; o.y = o23.u;
            reinterpret_cast<uint2*>(y)[ri] = o;
        } else {
            float w0 = attnp[0], w1 = attnp[1], w2 = attnp[2], w3 = attnp[3];
            float sq = sqdeg[nid];             // unscale y1'/y2'
            float4 e = reinterpret_cast<const float4*>(emb)[ri];
            uint2 v1 = reinterpret_cast<const uint2*>(y1)[ri];
            uint2 v2 = xv[ri];                 // y2' row of this node
            float4 r;
            r.x = w0 * e.x + sq * (w1 * h2lo(v1.x) + w2 * h2lo(v2.x)) + w3 * a0;
            r.y = w0 * e.y + sq * (w1 * h2hi(v1.x) + w2 * h2hi(v2.x)) + w3 * a1;
            r.z = w0 * e.z + sq * (w1 * h2lo(v1.y) + w2 * h2lo(v2.y)) + w3 * a2;
            r.w = w0 * e.w + sq * (w1 * h2hi(v1.y) + w2 * h2hi(v2.y)) + w3 * a3;
            reinterpret_cast<float4*>(out0)[ri] = e;
            reinterpret_cast<float4*>(acc)[ri] = r;
        }
    }
}

extern "C" void kernel_launch(void* const* d_in, const int* in_sizes, int n_in,
                              void* d_out, int out_size, void* d_ws, size_t ws_size,
                              hipStream_t stream) {
    const float* emb   = (const float*)d_in[0];
    const float* attw  = (const float*)d_in[1];
    const float* scale = (const float*)d_in[2];
    const float* attr  = (const float*)d_in[3];
    const int*   ei    = (const int*)d_in[4];
    const int* src = ei;
    const int* dst = ei + NE;

    float* out0 = (float*)d_out;
    float* acc  = out0 + (size_t)NN * ED;

    // workspace (~56 MB). part (27.3MB) dead after k_build -> aliased by
    // the fp16 x0/y1 buffers (2 x 12.8MB).
    const size_t SLOTS  = (size_t)NBUCK * CAP;    // 3,411,968 (part)
    const size_t PSLOTS = (size_t)NBUCK * PCAP;   // 3,713,024 (eq)
    char* ws = (char*)d_ws;
    size_t off = 0;
    float*  attn   = (float*)(ws + off); off += 256;
    int*    gcur   = (int*)(ws + off);   off += 1024;
    float*  dinvf  = (float*)(ws + off); off += ((size_t)NN * 4 + 255) & ~(size_t)255;
    float*  sqdeg  = (float*)(ws + off); off += ((size_t)NN * 4 + 255) & ~(size_t)255;
    int*    rowptr = (int*)(ws + off);   off += ((size_t)NN * 4 + 255) & ~(size_t)255;
    unsigned short* pdeg16 = (unsigned short*)(ws + off); off += ((size_t)NN * 2 + 255) & ~(size_t)255;
    char*   partc  = ws + off;           off += SLOTS * 8;
    unsigned long long* part = (unsigned long long*)partc;
    unsigned* eq   = (unsigned*)(ws + off); off += PSLOTS * 4;
    unsigned short* y2 = (unsigned short*)(ws + off); off += (size_t)NN * ED * 2;
    // aliases into dead part region (written only after k_build):
    unsigned short* x0 = (unsigned short*)partc;
    unsigned short* y1 = (unsigned short*)partc + (size_t)NN * ED;

    const int VB = (NN * ED / 4) / 256;        // 6250 exact (k_prep)
    const int GB = (NN * ED) / 256;            // 25000 exact
    const int PB = (NE + CHUNK - 1) / CHUNK;   // 391

    k_init<<<1, 256, 0, stream>>>(attw, attn, gcur);
    k_part<<<PB, PTH, 0, stream>>>(src, dst, attr, scale, gcur, part);
    k_build<<<NBUCK, 1024, 0, stream>>>(gcur, part, rowptr, pdeg16, dinvf, sqdeg, eq);
    // part dead from here; x0/y1 alias it
    k_prep<<<VB, 256, 0, stream>>>(emb, dinvf, x0);

    k_gather<false><<<GB, 256, 0, stream>>>(rowptr, pdeg16, eq, dinvf, sqdeg, x0, y1,
        nullptr, nullptr, nullptr, nullptr, nullptr);
    k_gather<false><<<GB, 256, 0, stream>>>(rowptr, pdeg16, eq, dinvf, sqdeg, y1, y2,
        nullptr, nullptr, nullptr, nullptr, nullptr);
    k_gather<true><<<GB, 256, 0, stream>>>(rowptr, pdeg16, eq, dinvf, sqdeg, y2, nullptr,
        y1, emb, attn, out0, acc);
}

// Round 17
// 218.103 us; speedup vs baseline: 1.6044x; 1.0396x over previous
//
#include <hip/hip_runtime.h>
#include <hip/hip_fp16.h>

#define NN 100000          // N_NODES
#define ED 64              // EMB_DIM
#define NE 3200000         // N_EDGES
#define BSH 9              // log2 nodes per bucket
#define BNODES 512
#define NBUCK 196          // ceil(NN/BNODES)
#define CAP 17408          // slots per bucket (mean 16327, +8 sigma), mult of 64
#define PCAP 18944         // CAP + 512*3 pad headroom, mult of 64
#define CHUNK 8192
#define PTH 512

union U32H2 { unsigned u; __half2 h; };
__device__ __forceinline__ float h2lo(unsigned u) { U32H2 c; c.u = u; return __low2float(c.h); }
__device__ __forceinline__ float h2hi(unsigned u) { U32H2 c; c.u = u; return __high2float(c.h); }

// softmax(attn weights) + init bucket cursors gcur[b] = b*CAP
__global__ void k_init(const float* __restrict__ w, float* __restrict__ attn,
                       int* __restrict__ gcur) {
    int t = threadIdx.x;
    if (t < NBUCK) gcur[t] = t * CAP;
    if (t == 0) {
        float m = fmaxf(fmaxf(w[0], w[1]), fmaxf(w[2], w[3]));
        float e0 = expf(w[0] - m), e1 = expf(w[1] - m), e2 = expf(w[2] - m), e3 = expf(w[3] - m);
        float s = e0 + e1 + e2 + e3;
        attn[0] = e0 / s; attn[1] = e1 / s; attn[2] = e2 / s; attn[3] = e3 / s;
    }
}

// pass 1: partition edges into fixed-CAP dst-buckets. 4 edges/thread.
// entry u64 = eattr fp16 <<32 | dl 9b <<17 | src 17b, eattr = exp(scale*attr)
__global__ void __launch_bounds__(PTH) k_part(const int* __restrict__ src,
        const int* __restrict__ dst, const float* __restrict__ attr,
        const float* __restrict__ scale,
        int* __restrict__ gcur, unsigned long long* __restrict__ part) {
    __shared__ unsigned long long stage[CHUNK];   // 64 KiB
    __shared__ int hist[NBUCK];
    __shared__ int lstart[NBUCK + 1];
    __shared__ int gbase[NBUCK];
    __shared__ unsigned char bkof[CHUNK];         // 8 KiB
    const int tid = threadIdx.x;
    const int base = blockIdx.x * CHUNK;
    const int n = min(CHUNK, NE - base);
    for (int i = tid; i < NBUCK; i += PTH) hist[i] = 0;
    __syncthreads();
    for (int i = tid * 4; i < n; i += PTH * 4) {
        int4 d4 = *reinterpret_cast<const int4*>(dst + base + i);
        atomicAdd(&hist[d4.x >> BSH], 1); atomicAdd(&hist[d4.y >> BSH], 1);
        atomicAdd(&hist[d4.z >> BSH], 1); atomicAdd(&hist[d4.w >> BSH], 1);
    }
    __syncthreads();
    if (tid < 64) {                                // exclusive scan of hist
        int carry = 0;
        #pragma unroll
        for (int g = 0; g < 4; ++g) {
            int b = g * 64 + tid;
            int v = (b < NBUCK) ? hist[b] : 0;
            int s = v;
            #pragma unroll
            for (int o = 1; o < 64; o <<= 1) { int t = __shfl_up(s, o, 64); if (tid >= o) s += t; }
            if (b < NBUCK) lstart[b] = carry + s - v;
            carry += __shfl(s, 63, 64);
        }
        if (tid == 0) lstart[NBUCK] = n;
    }
    __syncthreads();
    for (int b = tid; b < NBUCK; b += PTH) {
        int cnt = lstart[b + 1] - lstart[b];
        gbase[b] = atomicAdd(&gcur[b], cnt);
        hist[b] = lstart[b];
    }
    __syncthreads();
    const float sc = scale[0];
    for (int i = tid * 4; i < n; i += PTH * 4) {
        int4 s4 = *reinterpret_cast<const int4*>(src + base + i);
        int4 d4 = *reinterpret_cast<const int4*>(dst + base + i);
        float4 a4 = *reinterpret_cast<const float4*>(attr + base + i);
        #pragma unroll
        for (int k = 0; k < 4; ++k) {
            int s = (k == 0) ? s4.x : (k == 1) ? s4.y : (k == 2) ? s4.z : s4.w;
            int d = (k == 0) ? d4.x : (k == 1) ? d4.y : (k == 2) ? d4.z : d4.w;
            float a = (k == 0) ? a4.x : (k == 1) ? a4.y : (k == 2) ? a4.z : a4.w;
            unsigned short ea = __half_as_ushort(__float2half(expf(sc * a)));
            int bk = d >> BSH;
            int p = atomicAdd(&hist[bk], 1);
            stage[p] = ((unsigned long long)ea << 32)
                     | (unsigned)(s | ((d & (BNODES - 1)) << 17));
            bkof[p] = (unsigned char)bk;
        }
    }
    __syncthreads();
    for (int i = tid; i < n; i += PTH) {
        int bk = bkof[i];
        part[(size_t)gbase[bk] + (i - lstart[bk])] = stage[i];
    }
}

// merged build: per-bucket histogram -> padded scan -> placement.
// eq[p] = ( fp15(dinv[dst]*eattr) << 17 ) | src  — COMPLETE static weight
// (dinv[src] is folded into the x operand, not the weight). Also sqdeg[n].
__global__ void __launch_bounds__(1024) k_build(const int* __restrict__ gcur,
        const unsigned long long* __restrict__ part,
        int* __restrict__ rowptr, unsigned short* __restrict__ pdeg16,
        float* __restrict__ dinvf, float* __restrict__ sqdeg,
        unsigned* __restrict__ eq) {
    __shared__ int deg[BNODES];
    __shared__ int cur[BNODES];
    __shared__ float dli[BNODES];
    __shared__ int wsum[8];
    const int b = blockIdx.x, tid = threadIdx.x;
    const int rs = b * CAP, re = gcur[b];
    if (tid < BNODES) deg[tid] = 0;
    __syncthreads();
    for (int j = rs + tid; j < re; j += 1024) {
        unsigned lo = (unsigned)part[j];
        atomicAdd(&deg[(lo >> 17) & (BNODES - 1)], 1);
    }
    __syncthreads();
    int start = 0, pd = 0, d = 0;
    if (tid < BNODES) {
        const int lane = tid & 63, wv = tid >> 6;
        d = deg[tid];
        pd = (d + 3) & ~3;
        int x = pd;
        #pragma unroll
        for (int o = 1; o < 64; o <<= 1) { int t = __shfl_up(x, o, 64); if (lane >= o) x += t; }
        if (lane == 63) wsum[wv] = x;
        __syncthreads();
        if (tid < 8) {
            int orig = wsum[tid]; int t = orig;
            #pragma unroll
            for (int o = 1; o < 8; o <<= 1) { int u = __shfl_up(t, o, 64); if (tid >= o) t += u; }
            wsum[tid] = t - orig;
        }
        __syncthreads();
        int node = b * BNODES + tid;
        start = b * PCAP + wsum[wv] + (x - pd);
        cur[tid] = start;
        float dv = (d > 0) ? rsqrtf((float)d) : 0.0f;
        dli[tid] = dv;
        if (node < NN) {
            rowptr[node] = start;
            pdeg16[node] = (unsigned short)pd;
            dinvf[node] = dv;
            sqdeg[node] = (d > 0) ? sqrtf((float)d) : 0.0f;
        }
    } else {
        __syncthreads();
        __syncthreads();
    }
    __syncthreads();
    // placement pass
    for (int j = rs + tid; j < re; j += 1024) {
        unsigned long long v = part[j];
        unsigned lo = (unsigned)v;
        unsigned s = lo & 0x1FFFFu;
        int dl = (lo >> 17) & (BNODES - 1);
        float ea = __half2float(__ushort_as_half((unsigned short)(v >> 32)));
        float w = dli[dl] * ea;                    // >= 0, fp16 sign bit = 0
        unsigned hw = (unsigned)__half_as_ushort(__float2half(w));
        int p = atomicAdd(&cur[dl], 1);
        eq[p] = (hw << 17) | s;
    }
    __syncthreads();
    if (tid < BNODES) {                            // zero the <=3 pad slots per row
        int fin = start + pd;
        for (int p = cur[tid]; p < fin; ++p) eq[p] = 0u;
    }
}

// x0' = fp16( dinv[row] * emb ). grid = NN*ED/4/256 = 6250 exact
__global__ void k_prep(const float* __restrict__ emb, const float* __restrict__ dinvf,
                       unsigned short* __restrict__ x0) {
    int i = blockIdx.x * 256 + threadIdx.x;
    float dv = dinvf[i >> 4];
    float4 e = reinterpret_cast<const float4*>(emb)[i];
    ushort4 u;
    u.x = __half_as_ushort(__float2half(e.x * dv));
    u.y = __half_as_ushort(__float2half(e.y * dv));
    u.z = __half_as_ushort(__float2half(e.z * dv));
    u.w = __half_as_ushort(__float2half(e.w * dv));
    reinterpret_cast<ushort4*>(x0)[i] = u;
}

// gather: TWO nodes per wave (A=2w, B=2w+1), interleaved independent load
// chains -> 2x outstanding requests per wave. 4 lane-groups of 16 handle 4
// edges (a quad) per node per step; loop runs to max(pdA,pdB); the shorter
// node's surplus quads re-read its last quad with weight zeroed (uniform
// select, clamped index stays in-bounds).
// Non-FINAL: write y' = dinv[nid]*sum as fp16. FINAL: fused 4-way combine.
template <bool FINAL>
__global__ void __launch_bounds__(256) k_gather(const int* __restrict__ rowptr,
        const unsigned short* __restrict__ pdeg16,
        const unsigned* __restrict__ eq,
        const float* __restrict__ dinvf, const float* __restrict__ sqdeg,
        const unsigned short* __restrict__ x, unsigned short* __restrict__ y,
        const unsigned short* __restrict__ y1, const float* __restrict__ emb,
        const float* __restrict__ attnp, float* __restrict__ out0,
        float* __restrict__ acc) {
    int gt = blockIdx.x * 256 + threadIdx.x;   // grid = NN*32/256 = 12500 exact
    int wid = gt >> 6;                         // wave id; nodes 2w, 2w+1
    int nidA = wid * 2, nidB = nidA + 1;
    int lane = gt & 63;
    int g = lane >> 4;                         // edge slot 0..3 within quad
    int gi = lane & 15;                        // 4-dim chunk index
    int begA = __builtin_amdgcn_readfirstlane(rowptr[nidA]);
    int pdA  = __builtin_amdgcn_readfirstlane((int)pdeg16[nidA]);
    int begB = __builtin_amdgcn_readfirstlane(rowptr[nidB]);
    int pdB  = __builtin_amdgcn_readfirstlane((int)pdeg16[nidB]);
    int mx = max(pdA, pdB);
    const unsigned* eqg = eq + g;
    const uint2* xv = reinterpret_cast<const uint2*>(x);
    __half2 z = __float2half2_rn(0.0f);
    __half2 paA0 = z, paA1 = z, pbA0 = z, pbA1 = z;
    __half2 paB0 = z, paB1 = z, pbB0 = z, pbB1 = z;

#define QEN(BEG, PD, STEP, A0, A1) { \
    int jj = (BEG) + (((STEP) < (PD)) ? (STEP) : (PD) - 4); \
    unsigned eu = eqg[jj]; \
    unsigned s = eu & 0x1FFFFu; \
    unsigned wu = ((STEP) < (PD)) ? (eu >> 17) : 0u; \
    U32H2 wd; wd.u = __builtin_amdgcn_perm(wu, wu, 0x01000100u); \
    uint2 u = xv[(s << 4) | (unsigned)gi]; \
    U32H2 ux, uy; ux.u = u.x; uy.u = u.y; \
    A0 = __hfma2(wd.h, ux.h, A0); \
    A1 = __hfma2(wd.h, uy.h, A1); }

    int step = 0;
    int m32 = mx & ~31;
    for (; step < m32; step += 32) {
        QEN(begA, pdA, step +  0, paA0, paA1); QEN(begB, pdB, step +  0, paB0, paB1);
        QEN(begA, pdA, step +  4, pbA0, pbA1); QEN(begB, pdB, step +  4, pbB0, pbB1);
        QEN(begA, pdA, step +  8, paA0, paA1); QEN(begB, pdB, step +  8, paB0, paB1);
        QEN(begA, pdA, step + 12, pbA0, pbA1); QEN(begB, pdB, step + 12, pbB0, pbB1);
        QEN(begA, pdA, step + 16, paA0, paA1); QEN(begB, pdB, step + 16, paB0, paB1);
        QEN(begA, pdA, step + 20, pbA0, pbA1); QEN(begB, pdB, step + 20, pbB0, pbB1);
        QEN(begA, pdA, step + 24, paA0, paA1); QEN(begB, pdB, step + 24, paB0, paB1);
        QEN(begA, pdA, step + 28, pbA0, pbA1); QEN(begB, pdB, step + 28, pbB0, pbB1);
    }
    if (mx & 16) {
        QEN(begA, pdA, step +  0, paA0, paA1); QEN(begB, pdB, step +  0, paB0, paB1);
        QEN(begA, pdA, step +  4, pbA0, pbA1); QEN(begB, pdB, step +  4, pbB0, pbB1);
        QEN(begA, pdA, step +  8, paA0, paA1); QEN(begB, pdB, step +  8, paB0, paB1);
        QEN(begA, pdA, step + 12, pbA0, pbA1); QEN(begB, pdB, step + 12, pbB0, pbB1);
        step += 16;
    }
    if (mx & 8) {
        QEN(begA, pdA, step +  0, paA0, paA1); QEN(begB, pdB, step +  0, paB0, paB1);
        QEN(begA, pdA, step +  4, pbA0, pbA1); QEN(begB, pdB, step +  4, pbB0, pbB1);
        step += 8;
    }
    if (mx & 4) {
        QEN(begA, pdA, step, paA0, paA1); QEN(begB, pdB, step, paB0, paB1);
    }
#undef QEN

    float2 fa0, fa1, fb0, fb1;
    fa0 = __half22float2(paA0); fb0 = __half22float2(pbA0);
    fa1 = __half22float2(paA1); fb1 = __half22float2(pbA1);
    float aA0 = fa0.x + fb0.x, aA1 = fa0.y + fb0.y;
    float aA2 = fa1.x + fb1.x, aA3 = fa1.y + fb1.y;
    fa0 = __half22float2(paB0); fb0 = __half22float2(pbB0);
    fa1 = __half22float2(paB1); fb1 = __half22float2(pbB1);
    float aB0 = fa0.x + fb0.x, aB1 = fa0.y + fb0.y;
    float aB2 = fa1.x + fb1.x, aB3 = fa1.y + fb1.y;
    aA0 += __shfl_xor(aA0, 16, 64); aA0 += __shfl_xor(aA0, 32, 64);
    aA1 += __shfl_xor(aA1, 16, 64); aA1 += __shfl_xor(aA1, 32, 64);
    aA2 += __shfl_xor(aA2, 16, 64); aA2 += __shfl_xor(aA2, 32, 64);
    aA3 += __shfl_xor(aA3, 16, 64); aA3 += __shfl_xor(aA3, 32, 64);
    aB0 += __shfl_xor(aB0, 16, 64); aB0 += __shfl_xor(aB0, 32, 64);
    aB1 += __shfl_xor(aB1, 16, 64); aB1 += __shfl_xor(aB1, 32, 64);
    aB2 += __shfl_xor(aB2, 16, 64); aB2 += __shfl_xor(aB2, 32, 64);
    aB3 += __shfl_xor(aB3, 16, 64); aB3 += __shfl_xor(aB3, 32, 64);
    if (lane < 16) {
        unsigned riA = (unsigned)(nidA << 4) | (unsigned)gi;
        unsigned riB = (unsigned)(nidB << 4) | (unsigned)gi;
        if (!FINAL) {
            float dvA = dinvf[nidA], dvB = dinvf[nidB];
            U32H2 o01, o23;
            o01.h = __floats2half2_rn(aA0 * dvA, aA1 * dvA);
            o23.h = __floats2half2_rn(aA2 * dvA, aA3 * dvA);
            uint2 oA; oA.x = o01.u; oA.y = o23.u;
            reinterpret_cast<uint2*>(y)[riA] = oA;
            o01.h = __floats2half2_rn(aB0 * dvB, aB1 * dvB);
            o23.h = __floats2half2_rn(aB2 * dvB, aB3 * dvB);
            uint2 oB; oB.x = o01.u; oB.y = o23.u;
            reinterpret_cast<uint2*>(y)[riB] = oB;
        } else {
            float w0 = attnp[0], w1 = attnp[1], w2 = attnp[2], w3 = attnp[3];
            {
                float sq = sqdeg[nidA];
                float4 e = reinterpret_cast<const float4*>(emb)[riA];
                uint2 v1 = reinterpret_cast<const uint2*>(y1)[riA];
                uint2 v2 = xv[riA];
                float4 r;
                r.x = w0 * e.x + sq * (w1 * h2lo(v1.x) + w2 * h2lo(v2.x)) + w3 * aA0;
                r.y = w0 * e.y + sq * (w1 * h2hi(v1.x) + w2 * h2hi(v2.x)) + w3 * aA1;
                r.z = w0 * e.z + sq * (w1 * h2lo(v1.y) + w2 * h2lo(v2.y)) + w3 * aA2;
                r.w = w0 * e.w + sq * (w1 * h2hi(v1.y) + w2 * h2hi(v2.y)) + w3 * aA3;
                reinterpret_cast<float4*>(out0)[riA] = e;
                reinterpret_cast<float4*>(acc)[riA] = r;
            }
            {
                float sq = sqdeg[nidB];
                float4 e = reinterpret_cast<const float4*>(emb)[riB];
                uint2 v1 = reinterpret_cast<const uint2*>(y1)[riB];
                uint2 v2 = xv[riB];
                float4 r;
                r.x = w0 * e.x + sq * (w1 * h2lo(v1.x) + w2 * h2lo(v2.x)) + w3 * aB0;
                r.y = w0 * e.y + sq * (w1 * h2hi(v1.x) + w2 * h2hi(v2.x)) + w3 * aB1;
                r.z = w0 * e.z + sq * (w1 * h2lo(v1.y) + w2 * h2lo(v2.y)) + w3 * aB2;
                r.w = w0 * e.w + sq * (w1 * h2hi(v1.y) + w2 * h2hi(v2.y)) + w3 * aB3;
                reinterpret_cast<float4*>(out0)[riB] = e;
                reinterpret_cast<float4*>(acc)[riB] = r;
            }
        }
    }
}

extern "C" void kernel_launch(void* const* d_in, const int* in_sizes, int n_in,
                              void* d_out, int out_size, void* d_ws, size_t ws_size,
                              hipStream_t stream) {
    const float* emb   = (const float*)d_in[0];
    const float* attw  = (const float*)d_in[1];
    const float* scale = (const float*)d_in[2];
    const float* attr  = (const float*)d_in[3];
    const int*   ei    = (const int*)d_in[4];
    const int* src = ei;
    const int* dst = ei + NE;

    float* out0 = (float*)d_out;
    float* acc  = out0 + (size_t)NN * ED;

    // workspace (~56 MB). part (27.3MB) dead after k_build -> aliased by
    // the fp16 x0/y1 buffers (2 x 12.8MB).
    const size_t SLOTS  = (size_t)NBUCK * CAP;    // 3,411,968 (part)
    const size_t PSLOTS = (size_t)NBUCK * PCAP;   // 3,713,024 (eq)
    char* ws = (char*)d_ws;
    size_t off = 0;
    float*  attn   = (float*)(ws + off); off += 256;
    int*    gcur   = (int*)(ws + off);   off += 1024;
    float*  dinvf  = (float*)(ws + off); off += ((size_t)NN * 4 + 255) & ~(size_t)255;
    float*  sqdeg  = (float*)(ws + off); off += ((size_t)NN * 4 + 255) & ~(size_t)255;
    int*    rowptr = (int*)(ws + off);   off += ((size_t)NN * 4 + 255) & ~(size_t)255;
    unsigned short* pdeg16 = (unsigned short*)(ws + off); off += ((size_t)NN * 2 + 255) & ~(size_t)255;
    char*   partc  = ws + off;           off += SLOTS * 8;
    unsigned long long* part = (unsigned long long*)partc;
    unsigned* eq   = (unsigned*)(ws + off); off += PSLOTS * 4;
    unsigned short* y2 = (unsigned short*)(ws + off); off += (size_t)NN * ED * 2;
    // aliases into dead part region (written only after k_build):
    unsigned short* x0 = (unsigned short*)partc;
    unsigned short* y1 = (unsigned short*)partc + (size_t)NN * ED;

    const int VB = (NN * ED / 4) / 256;        // 6250 exact (k_prep)
    const int GB2 = NN / 8;                    // 12500 exact (2 nodes/wave)
    const int PB = (NE + CHUNK - 1) / CHUNK;   // 391

    k_init<<<1, 256, 0, stream>>>(attw, attn, gcur);
    k_part<<<PB, PTH, 0, stream>>>(src, dst, attr, scale, gcur, part);
    k_build<<<NBUCK, 1024, 0, stream>>>(gcur, part, rowptr, pdeg16, dinvf, sqdeg, eq);
    // part dead from here; x0/y1 alias it
    k_prep<<<VB, 256, 0, stream>>>(emb, dinvf, x0);

    k_gather<false><<<GB2, 256, 0, stream>>>(rowptr, pdeg16, eq, dinvf, sqdeg, x0, y1,
        nullptr, nullptr, nullptr, nullptr, nullptr);
    k_gather<false><<<GB2, 256, 0, stream>>>(rowptr, pdeg16, eq, dinvf, sqdeg, y1, y2,
        nullptr, nullptr, nullptr, nullptr, nullptr);
    k_gather<true><<<GB2, 256, 0, stream>>>(rowptr, pdeg16, eq, dinvf, sqdeg, y2, nullptr,
        y1, emb, attn, out0, acc);
}